// Round 14
// baseline (609.156 us; speedup 1.0000x reference)
//
#include <hip/hip_runtime.h>

#define U_N 100000
#define I_N 50000
#define D_N 128
#define B_N 4
#define E_N 500000
#define NEDGE (B_N * E_N)            // 2,000,000
#define NKEYU (4 * U_N)              // keys u*4+b
#define NKEYS (NKEYU + 4 * I_N)      // 600,000
#define NMEMB (2 * NEDGE)            // 4,000,000
#define SCHUNK 2048
#define SNBLK ((NKEYS + SCHUNK - 1) / SCHUNK)   // 293
#define TBI ((I_N + 31) / 32)        // transform blocks (item side)
#define TBU ((U_N + 31) / 32)        // transform blocks (user side)
#define CB  ((NMEMB + 255) / 256)    // count/fill blocks
#define NZ4 ((NKEYS + 4) / 4)        // int4 count for offs zeroing

typedef float f32x2 __attribute__((ext_vector_type(2)));

// round-to-nearest-even-ish bf16 pack of two floats -> uint (lo=a, hi=b)
__device__ inline unsigned int pack_bf16(float a, float b) {
    unsigned int ua = __float_as_uint(a);
    ua += 0x7FFFu + ((ua >> 16) & 1u);
    unsigned int ub = __float_as_uint(b);
    ub += 0x7FFFu + ((ub >> 16) & 1u);
    return (ua >> 16) | (ub & 0xFFFF0000u);
}

// ---------------------------------------------------------------------------
// Zero offs[] + sentinel pairs (must fully precede the count atomics).
// ---------------------------------------------------------------------------
__global__ __launch_bounds__(256) void zero_kernel(int4* __restrict__ offs4,
                                                   int2* __restrict__ sentinel)
{
    int t = blockIdx.x * 256 + threadIdx.x;
    if (t < NZ4) offs4[t] = make_int4(0, 0, 0, 0);
    if (t == 0) { sentinel[0] = make_int2(0, 0); sentinel[1] = make_int2(0, 0); }
}

// ---------------------------------------------------------------------------
// Fused transform + count. Transform role: Y = X @ W packed bf16, W staged
// in 32 KB LDS via two column-half passes (f32 precision; X row re-read is
// L2-hit) so count-role blocks keep 5 blocks/CU occupancy. Count role:
// one membership per thread; atomic return value = rank within bucket.
// The two roles are independent; count's atomic latency hides under the
// transform's VALU work.
// ---------------------------------------------------------------------------
__global__ __launch_bounds__(256) void tc_kernel(
    const float* __restrict__ item_emb, const float* __restrict__ user_emb,
    const float* __restrict__ u_w, const float* __restrict__ i_w,
    unsigned int* __restrict__ tA, unsigned int* __restrict__ tB,
    const int* __restrict__ eu, const int* __restrict__ ei,
    int* __restrict__ offs, int* __restrict__ rank_u, int* __restrict__ rank_i)
{
    __shared__ float wlds[D_N][64];   // 32 KB: one column-half of W

    if (blockIdx.x >= TBI + TBU) {
        // ---- count role ----
        int t = (blockIdx.x - TBI - TBU) * 256 + threadIdx.x;
        if (t >= NMEMB) return;
        if (t < NEDGE) {
            int e = t;
            int key = eu[e] * 4 + e / E_N;
            rank_u[e] = atomicAdd(&offs[key], 1);
        } else {
            int e = t - NEDGE;
            int key = NKEYU + ei[e] * 4 + e / E_N;
            rank_i[e] = atomicAdd(&offs[key], 1);
        }
        return;
    }

    // ---- transform role ----
    const float* X; const float* W; unsigned int* Y; int N; int blk;
    if (blockIdx.x < TBI) {
        X = item_emb; W = u_w; Y = tA; N = I_N; blk = blockIdx.x;
    } else {
        X = user_emb; W = i_w; Y = tB; N = U_N; blk = blockIdx.x - TBI;
    }

    int rr = threadIdx.x & 31;
    int cg = threadIdx.x >> 5;        // 0..7 -> 8 output cols each
    int c0 = cg * 8;
    int r  = blk * 32 + rr;
    bool valid = (r < N);
    int rc = valid ? r : (N - 1);
    const float* xrow = X + (size_t)rc * D_N;

    #pragma unroll
    for (int h = 0; h < 2; ++h) {
        __syncthreads();   // protect LDS reuse between passes
        // stage W[:, h*64 .. h*64+63]: W row stride = 32 float4s
        for (int idx = threadIdx.x; idx < D_N * 16; idx += 256) {
            int row = idx >> 4, c4 = idx & 15;
            *reinterpret_cast<float4*>(&wlds[row][c4 * 4]) =
                reinterpret_cast<const float4*>(W)[row * 32 + h * 16 + c4];
        }
        __syncthreads();

        float4 acc0 = make_float4(0.f, 0.f, 0.f, 0.f);
        float4 acc1 = make_float4(0.f, 0.f, 0.f, 0.f);
        for (int k4 = 0; k4 < D_N / 4; ++k4) {
            float4 a = *reinterpret_cast<const float4*>(xrow + k4 * 4);
            #pragma unroll
            for (int kk = 0; kk < 4; ++kk) {
                float ak = (kk == 0) ? a.x : (kk == 1) ? a.y
                         : (kk == 2) ? a.z : a.w;
                const float4 w0 = *reinterpret_cast<const float4*>(
                    &wlds[k4 * 4 + kk][c0]);
                const float4 w1 = *reinterpret_cast<const float4*>(
                    &wlds[k4 * 4 + kk][c0 + 4]);
                acc0.x += ak * w0.x; acc0.y += ak * w0.y;
                acc0.z += ak * w0.z; acc0.w += ak * w0.w;
                acc1.x += ak * w1.x; acc1.y += ak * w1.y;
                acc1.z += ak * w1.z; acc1.w += ak * w1.w;
            }
        }
        if (valid) {
            unsigned int* yrow = Y + (size_t)r * (D_N / 2) + (h * 64 + c0) / 2;
            yrow[0] = pack_bf16(acc0.x, acc0.y);
            yrow[1] = pack_bf16(acc0.z, acc0.w);
            yrow[2] = pack_bf16(acc1.x, acc1.y);
            yrow[3] = pack_bf16(acc1.z, acc1.w);
        }
    }
}

// ---------------------------------------------------------------------------
// In-place hierarchical exclusive scan over offs[NKEYS].
// ---------------------------------------------------------------------------
__global__ __launch_bounds__(256) void scan1_kernel(
    int* __restrict__ offs, int* __restrict__ bsum)
{
    __shared__ int s[256];
    int base = blockIdx.x * SCHUNK + threadIdx.x * 8;
    int v[8]; int tsum = 0;
    #pragma unroll
    for (int j = 0; j < 8; ++j) {
        int idx = base + j;
        v[j] = (idx < NKEYS) ? offs[idx] : 0;
        tsum += v[j];
    }
    s[threadIdx.x] = tsum; __syncthreads();
    for (int off = 1; off < 256; off <<= 1) {
        int t = (threadIdx.x >= off) ? s[threadIdx.x - off] : 0;
        __syncthreads(); s[threadIdx.x] += t; __syncthreads();
    }
    int excl = s[threadIdx.x] - tsum;
    if (threadIdx.x == 255) bsum[blockIdx.x] = s[255];
    int run = excl;
    #pragma unroll
    for (int j = 0; j < 8; ++j) {
        int idx = base + j;
        if (idx < NKEYS) offs[idx] = run;
        run += v[j];
    }
}

__global__ __launch_bounds__(512) void scan2_kernel(int* __restrict__ bsum,
                                                    int* __restrict__ offs)
{
    __shared__ int s[512];
    int v = (threadIdx.x < SNBLK) ? bsum[threadIdx.x] : 0;
    s[threadIdx.x] = v; __syncthreads();
    for (int off = 1; off < 512; off <<= 1) {
        int t = (threadIdx.x >= off) ? s[threadIdx.x - off] : 0;
        __syncthreads(); s[threadIdx.x] += t; __syncthreads();
    }
    if (threadIdx.x < SNBLK) bsum[threadIdx.x] = s[threadIdx.x] - v;
    if (threadIdx.x == 511) offs[NKEYS] = s[511];
}

__global__ __launch_bounds__(256) void scan3_kernel(int* __restrict__ offs,
                                                    const int* __restrict__ bsum)
{
    int add = bsum[blockIdx.x];
    int base = blockIdx.x * SCHUNK + threadIdx.x * 8;
    #pragma unroll
    for (int j = 0; j < 8; ++j) {
        int idx = base + j;
        if (idx < NKEYS) offs[idx] += add;
    }
}

// ---------------------------------------------------------------------------
// Atomic-free fill: pos = offs[key] + precomputed rank.
// ---------------------------------------------------------------------------
__global__ __launch_bounds__(256) void fill_kernel(
    const int* __restrict__ eu, const int* __restrict__ ei,
    const float* __restrict__ ew,
    const int* __restrict__ offs,
    const int* __restrict__ rank_u, const int* __restrict__ rank_i,
    int2* __restrict__ pairs)
{
    int t = blockIdx.x * 256 + threadIdx.x;
    if (t >= NMEMB) return;
    if (t < NEDGE) {
        int e = t;
        int b = e / E_N;
        int key = eu[e] * 4 + b;
        int pos = offs[key] + rank_u[e];
        pairs[pos] = make_int2(ei[e], __float_as_int(ew[e]));
    } else {
        int e = t - NEDGE;
        int b = e / E_N;
        int key = NKEYU + ei[e] * 4 + b;
        int pos = offs[key] + rank_i[e];
        pairs[pos] = make_int2(eu[e], __float_as_int(ew[e]));
    }
}

// ---------------------------------------------------------------------------
// Fused gather: one wave per destination row; lane owns 2 dims (1 uint of
// 2 bf16). 4 behavior buckets in lockstep, x2-unrolled: 8 memberships in
// flight (8 aligned int2 pair loads + 8 T-row loads). Dead/odd-tail slots
// clamp to the PREVIOUS valid index -> re-read same pair & same T row
// (L2 hits, zero extra HBM). All wave-uniform control in SGPRs via
// readfirstlane. NT stores keep L2/L3 for the bf16 row pool.
// ---------------------------------------------------------------------------
__global__ __launch_bounds__(256) void gather_kernel(
    const unsigned int* __restrict__ tA, const unsigned int* __restrict__ tB,
    const int2* __restrict__ pairs, const int* __restrict__ offs,
    float* __restrict__ single_u, float* __restrict__ multi_u,
    float* __restrict__ single_i, float* __restrict__ multi_i,
    const float* __restrict__ alpha_p)
{
    int rg = blockIdx.x * 4 + (threadIdx.x >> 6);
    if (rg >= U_N + I_N) return;
    bool uside = rg < U_N;
    int r = uside ? rg : rg - U_N;
    const unsigned int* T = uside ? tA : tB;
    float* single  = uside ? single_u : single_i;
    float* multi   = uside ? multi_u : multi_i;
    int N  = uside ? U_N : I_N;
    int k0 = uside ? r * 4 : NKEYU + r * 4;

    float alpha = alpha_p[0];
    int lane = threadIdx.x & 63;

    int o0 = __builtin_amdgcn_readfirstlane(offs[k0]);
    int o1 = __builtin_amdgcn_readfirstlane(offs[k0 + 1]);
    int o2 = __builtin_amdgcn_readfirstlane(offs[k0 + 2]);
    int o3 = __builtin_amdgcn_readfirstlane(offs[k0 + 3]);
    int o4 = __builtin_amdgcn_readfirstlane(offs[k0 + 4]);
    int p0 = o0, p1 = o1, p2 = o2, p3 = o3;

    float ax0 = 0.f, ay0 = 0.f, ax1 = 0.f, ay1 = 0.f;
    float ax2 = 0.f, ay2 = 0.f, ax3 = 0.f, ay3 = 0.f;

    while ((p0 < o1) | (p1 < o2) | (p2 < o3) | (p3 < o4)) {
        int a0 = p0 < o1, b0 = (p0 + 1) < o1;
        int a1 = p1 < o2, b1 = (p1 + 1) < o2;
        int a2 = p2 < o3, b2 = (p2 + 1) < o3;
        int a3 = p3 < o4, b3 = (p3 + 1) < o4;
        // a-slot clamps to bucket-group start; b-slot clamps to a-slot
        // (same pair, same T row -> pure cache hits, no wasted HBM).
        int i0a = a0 ? p0 : o0;         int i0b = b0 ? (p0 + 1) : i0a;
        int i1a = a1 ? p1 : o0;         int i1b = b1 ? (p1 + 1) : i1a;
        int i2a = a2 ? p2 : o0;         int i2b = b2 ? (p2 + 1) : i2a;
        int i3a = a3 ? p3 : o0;         int i3b = b3 ? (p3 + 1) : i3a;
        int2 q0a = pairs[i0a], q0b = pairs[i0b];
        int2 q1a = pairs[i1a], q1b = pairs[i1b];
        int2 q2a = pairs[i2a], q2b = pairs[i2b];
        int2 q3a = pairs[i3a], q3b = pairs[i3b];
        int sx0a = __builtin_amdgcn_readfirstlane(q0a.x);
        int sw0a = __builtin_amdgcn_readfirstlane(q0a.y);
        int sx0b = __builtin_amdgcn_readfirstlane(q0b.x);
        int sw0b = __builtin_amdgcn_readfirstlane(q0b.y);
        int sx1a = __builtin_amdgcn_readfirstlane(q1a.x);
        int sw1a = __builtin_amdgcn_readfirstlane(q1a.y);
        int sx1b = __builtin_amdgcn_readfirstlane(q1b.x);
        int sw1b = __builtin_amdgcn_readfirstlane(q1b.y);
        int sx2a = __builtin_amdgcn_readfirstlane(q2a.x);
        int sw2a = __builtin_amdgcn_readfirstlane(q2a.y);
        int sx2b = __builtin_amdgcn_readfirstlane(q2b.x);
        int sw2b = __builtin_amdgcn_readfirstlane(q2b.y);
        int sx3a = __builtin_amdgcn_readfirstlane(q3a.x);
        int sw3a = __builtin_amdgcn_readfirstlane(q3a.y);
        int sx3b = __builtin_amdgcn_readfirstlane(q3b.x);
        int sw3b = __builtin_amdgcn_readfirstlane(q3b.y);
        unsigned int d0a = T[(size_t)sx0a * (D_N / 2) + lane];
        unsigned int d0b = T[(size_t)sx0b * (D_N / 2) + lane];
        unsigned int d1a = T[(size_t)sx1a * (D_N / 2) + lane];
        unsigned int d1b = T[(size_t)sx1b * (D_N / 2) + lane];
        unsigned int d2a = T[(size_t)sx2a * (D_N / 2) + lane];
        unsigned int d2b = T[(size_t)sx2b * (D_N / 2) + lane];
        unsigned int d3a = T[(size_t)sx3a * (D_N / 2) + lane];
        unsigned int d3b = T[(size_t)sx3b * (D_N / 2) + lane];
        float w0a = a0 ? __int_as_float(sw0a) : 0.f;
        float w0b = b0 ? __int_as_float(sw0b) : 0.f;
        float w1a = a1 ? __int_as_float(sw1a) : 0.f;
        float w1b = b1 ? __int_as_float(sw1b) : 0.f;
        float w2a = a2 ? __int_as_float(sw2a) : 0.f;
        float w2b = b2 ? __int_as_float(sw2b) : 0.f;
        float w3a = a3 ? __int_as_float(sw3a) : 0.f;
        float w3b = b3 ? __int_as_float(sw3b) : 0.f;
        ax0 += w0a * __uint_as_float(d0a << 16)
             + w0b * __uint_as_float(d0b << 16);
        ay0 += w0a * __uint_as_float(d0a & 0xFFFF0000u)
             + w0b * __uint_as_float(d0b & 0xFFFF0000u);
        ax1 += w1a * __uint_as_float(d1a << 16)
             + w1b * __uint_as_float(d1b << 16);
        ay1 += w1a * __uint_as_float(d1a & 0xFFFF0000u)
             + w1b * __uint_as_float(d1b & 0xFFFF0000u);
        ax2 += w2a * __uint_as_float(d2a << 16)
             + w2b * __uint_as_float(d2b << 16);
        ay2 += w2a * __uint_as_float(d2a & 0xFFFF0000u)
             + w2b * __uint_as_float(d2b & 0xFFFF0000u);
        ax3 += w3a * __uint_as_float(d3a << 16)
             + w3b * __uint_as_float(d3b << 16);
        ay3 += w3a * __uint_as_float(d3a & 0xFFFF0000u)
             + w3b * __uint_as_float(d3b & 0xFFFF0000u);
        p0 += a0 + b0; p1 += a1 + b1; p2 += a2 + b2; p3 += a3 + b3;
    }

    float mx = 0.25f * (ax0 + ax1 + ax2 + ax3);
    float my = 0.25f * (ay0 + ay1 + ay2 + ay3);

    f32x2 o;
    o.x = ax0 >= 0.f ? ax0 : alpha * ax0;
    o.y = ay0 >= 0.f ? ay0 : alpha * ay0;
    __builtin_nontemporal_store(o, reinterpret_cast<f32x2*>(
        single + ((size_t)0 * N + r) * D_N + lane * 2));
    o.x = ax1 >= 0.f ? ax1 : alpha * ax1;
    o.y = ay1 >= 0.f ? ay1 : alpha * ay1;
    __builtin_nontemporal_store(o, reinterpret_cast<f32x2*>(
        single + ((size_t)1 * N + r) * D_N + lane * 2));
    o.x = ax2 >= 0.f ? ax2 : alpha * ax2;
    o.y = ay2 >= 0.f ? ay2 : alpha * ay2;
    __builtin_nontemporal_store(o, reinterpret_cast<f32x2*>(
        single + ((size_t)2 * N + r) * D_N + lane * 2));
    o.x = ax3 >= 0.f ? ax3 : alpha * ax3;
    o.y = ay3 >= 0.f ? ay3 : alpha * ay3;
    __builtin_nontemporal_store(o, reinterpret_cast<f32x2*>(
        single + ((size_t)3 * N + r) * D_N + lane * 2));

    o.x = mx >= 0.f ? mx : alpha * mx;
    o.y = my >= 0.f ? my : alpha * my;
    __builtin_nontemporal_store(o, reinterpret_cast<f32x2*>(
        multi + (size_t)r * D_N + lane * 2));
}

extern "C" void kernel_launch(void* const* d_in, const int* in_sizes, int n_in,
                              void* d_out, int out_size, void* d_ws, size_t ws_size,
                              hipStream_t stream) {
    const float* user_emb = (const float*)d_in[0];
    const float* item_emb = (const float*)d_in[1];
    const int*   eu       = (const int*)d_in[2];
    const int*   ei       = (const int*)d_in[3];
    const float* ew       = (const float*)d_in[4];
    const float* u_w      = (const float*)d_in[5];
    const float* i_w      = (const float*)d_in[6];
    const float* alpha    = (const float*)d_in[7];

    float* out      = (float*)d_out;
    float* multi_u  = out;                                      // [U][D]
    float* multi_i  = out + (size_t)U_N * D_N;                  // [I][D]
    float* single_u = out + (size_t)(U_N + I_N) * D_N;          // [B][U][D]
    float* single_i = single_u + (size_t)B_N * U_N * D_N;       // [B][I][D]

    // ranks live in multi_i's slot (consumed by fill; gather writes after).
    int* rank_u = (int*)multi_i;                                // 8 MB
    int* rank_i = rank_u + NEDGE;                               // 8 MB

    // d_ws: offs | bsum | pairs(+2 sentinels) | tA(bf16) | tB(bf16) (~73 MB)
    int*  offs  = (int*)d_ws;                                   // NKEYS+4
    int*  bsum  = offs + (NKEYS + 4);                           // 512
    int2* pairs = (int2*)((char*)d_ws + ((((NKEYS + 4 + 512) * 4) + 255) & ~255));
    unsigned int* tA = (unsigned int*)(pairs + NMEMB + 2);      // [I][64] 12.8 MB
    unsigned int* tB = tA + (size_t)I_N * (D_N / 2);            // [U][64] 25.6 MB

    zero_kernel<<<(NZ4 + 255) / 256, 256, 0, stream>>>((int4*)offs,
                                                       pairs + NMEMB);
    tc_kernel<<<TBI + TBU + CB, 256, 0, stream>>>(
        item_emb, user_emb, u_w, i_w, tA, tB, eu, ei, offs, rank_u, rank_i);
    scan1_kernel<<<SNBLK, 256, 0, stream>>>(offs, bsum);
    scan2_kernel<<<1, 512, 0, stream>>>(bsum, offs);
    scan3_kernel<<<SNBLK, 256, 0, stream>>>(offs, bsum);
    fill_kernel<<<CB, 256, 0, stream>>>(eu, ei, ew, offs,
                                        rank_u, rank_i, pairs);
    gather_kernel<<<(U_N + I_N + 3) / 4, 256, 0, stream>>>(
        tA, tB, pairs, offs,
        single_u, multi_u, single_i, multi_i, alpha);
}

// Round 15
// 595.193 us; speedup vs baseline: 1.0235x; 1.0235x over previous
//
#include <hip/hip_runtime.h>

#define U_N 100000
#define I_N 50000
#define D_N 128
#define B_N 4
#define E_N 500000
#define NEDGE (B_N * E_N)            // 2,000,000
#define NKEYU (4 * U_N)              // keys u*4+b
#define NKEYS (NKEYU + 4 * I_N)      // 600,000
#define NMEMB (2 * NEDGE)            // 4,000,000
#define SCHUNK 2048
#define SNBLK ((NKEYS + SCHUNK - 1) / SCHUNK)   // 293
#define TBI ((I_N + 31) / 32)        // transform blocks (item side)
#define TBU ((U_N + 31) / 32)        // transform blocks (user side)
#define CB  ((NMEMB + 255) / 256)    // count/fill blocks
#define NZ4 ((NKEYS + 4) / 4)        // int4 count for offs zeroing
#define ZB  ((NZ4 + 255) / 256)      // zero-role blocks

typedef float f32x2 __attribute__((ext_vector_type(2)));

// round-to-nearest-even-ish bf16 pack of two floats -> uint (lo=a, hi=b)
__device__ inline unsigned int pack_bf16(float a, float b) {
    unsigned int ua = __float_as_uint(a);
    ua += 0x7FFFu + ((ua >> 16) & 1u);
    unsigned int ub = __float_as_uint(b);
    ub += 0x7FFFu + ((ub >> 16) & 1u);
    return (ua >> 16) | (ub & 0xFFFF0000u);
}

// ---------------------------------------------------------------------------
// Fused: tA = item_emb @ u_w (bf16), tB = user_emb @ i_w (bf16) with
// LDS-staged W, plus zero-role blocks clearing offs[] and the sentinels.
// (transform+count fusion rejected twice: r12 no-LDS L2 storm, r14 LDS
//  occupancy tax on count-role blocks. Keep roles in separate kernels.)
// ---------------------------------------------------------------------------
__global__ __launch_bounds__(256) void transform2_kernel(
    const float* __restrict__ item_emb, const float* __restrict__ user_emb,
    const float* __restrict__ u_w, const float* __restrict__ i_w,
    unsigned int* __restrict__ tA, unsigned int* __restrict__ tB,
    int4* __restrict__ offs4, int2* __restrict__ sentinel)
{
    __shared__ float wlds[D_N][D_N];

    const float* X; const float* W; unsigned int* Y; int N; int blk;
    if (blockIdx.x < TBI) {
        X = item_emb; W = u_w; Y = tA; N = I_N; blk = blockIdx.x;
    } else if (blockIdx.x < TBI + TBU) {
        X = user_emb; W = i_w; Y = tB; N = U_N; blk = blockIdx.x - TBI;
    } else {
        int t = (blockIdx.x - TBI - TBU) * 256 + threadIdx.x;
        if (t < NZ4) offs4[t] = make_int4(0, 0, 0, 0);
        if (t == 0) { sentinel[0] = make_int2(0, 0); sentinel[1] = make_int2(0, 0); }
        return;
    }

    for (int idx = threadIdx.x; idx < D_N * D_N / 4; idx += 256)
        reinterpret_cast<float4*>(&wlds[0][0])[idx] =
            reinterpret_cast<const float4*>(W)[idx];
    __syncthreads();

    int rr = threadIdx.x & 31;
    int cg = threadIdx.x >> 5;
    int c0 = cg * 16;
    int r  = blk * 32 + rr;
    bool valid = (r < N);
    int rc = valid ? r : (N - 1);
    const float* xrow = X + (size_t)rc * D_N;

    float4 acc[4];
    #pragma unroll
    for (int c = 0; c < 4; ++c) acc[c] = make_float4(0.f, 0.f, 0.f, 0.f);

    for (int k4 = 0; k4 < D_N / 4; ++k4) {
        float4 a = *reinterpret_cast<const float4*>(xrow + k4 * 4);
        #pragma unroll
        for (int kk = 0; kk < 4; ++kk) {
            float ak = (kk == 0) ? a.x : (kk == 1) ? a.y : (kk == 2) ? a.z : a.w;
            #pragma unroll
            for (int c = 0; c < 4; ++c) {
                const float4 wv = *reinterpret_cast<const float4*>(
                    &wlds[k4 * 4 + kk][c0 + c * 4]);
                acc[c].x += ak * wv.x;
                acc[c].y += ak * wv.y;
                acc[c].z += ak * wv.z;
                acc[c].w += ak * wv.w;
            }
        }
    }
    if (valid) {
        unsigned int* yrow = Y + (size_t)r * (D_N / 2) + c0 / 2;
        #pragma unroll
        for (int c = 0; c < 4; ++c) {
            yrow[2 * c]     = pack_bf16(acc[c].x, acc[c].y);
            yrow[2 * c + 1] = pack_bf16(acc[c].z, acc[c].w);
        }
    }
}

// ---------------------------------------------------------------------------
// Count + rank: one membership per thread; atomic return value = rank.
// ---------------------------------------------------------------------------
__global__ __launch_bounds__(256) void count_kernel(
    const int* __restrict__ eu, const int* __restrict__ ei,
    int* __restrict__ offs, int* __restrict__ rank_u, int* __restrict__ rank_i)
{
    int t = blockIdx.x * 256 + threadIdx.x;
    if (t >= NMEMB) return;
    if (t < NEDGE) {
        int e = t;
        int key = eu[e] * 4 + e / E_N;
        rank_u[e] = atomicAdd(&offs[key], 1);
    } else {
        int e = t - NEDGE;
        int key = NKEYU + ei[e] * 4 + e / E_N;
        rank_i[e] = atomicAdd(&offs[key], 1);
    }
}

// ---------------------------------------------------------------------------
// In-place hierarchical exclusive scan over offs[NKEYS].
// ---------------------------------------------------------------------------
__global__ __launch_bounds__(256) void scan1_kernel(
    int* __restrict__ offs, int* __restrict__ bsum)
{
    __shared__ int s[256];
    int base = blockIdx.x * SCHUNK + threadIdx.x * 8;
    int v[8]; int tsum = 0;
    #pragma unroll
    for (int j = 0; j < 8; ++j) {
        int idx = base + j;
        v[j] = (idx < NKEYS) ? offs[idx] : 0;
        tsum += v[j];
    }
    s[threadIdx.x] = tsum; __syncthreads();
    for (int off = 1; off < 256; off <<= 1) {
        int t = (threadIdx.x >= off) ? s[threadIdx.x - off] : 0;
        __syncthreads(); s[threadIdx.x] += t; __syncthreads();
    }
    int excl = s[threadIdx.x] - tsum;
    if (threadIdx.x == 255) bsum[blockIdx.x] = s[255];
    int run = excl;
    #pragma unroll
    for (int j = 0; j < 8; ++j) {
        int idx = base + j;
        if (idx < NKEYS) offs[idx] = run;
        run += v[j];
    }
}

__global__ __launch_bounds__(512) void scan2_kernel(int* __restrict__ bsum,
                                                    int* __restrict__ offs)
{
    __shared__ int s[512];
    int v = (threadIdx.x < SNBLK) ? bsum[threadIdx.x] : 0;
    s[threadIdx.x] = v; __syncthreads();
    for (int off = 1; off < 512; off <<= 1) {
        int t = (threadIdx.x >= off) ? s[threadIdx.x - off] : 0;
        __syncthreads(); s[threadIdx.x] += t; __syncthreads();
    }
    if (threadIdx.x < SNBLK) bsum[threadIdx.x] = s[threadIdx.x] - v;
    if (threadIdx.x == 511) offs[NKEYS] = s[511];
}

__global__ __launch_bounds__(256) void scan3_kernel(int* __restrict__ offs,
                                                    const int* __restrict__ bsum)
{
    int add = bsum[blockIdx.x];
    int base = blockIdx.x * SCHUNK + threadIdx.x * 8;
    #pragma unroll
    for (int j = 0; j < 8; ++j) {
        int idx = base + j;
        if (idx < NKEYS) offs[idx] += add;
    }
}

// ---------------------------------------------------------------------------
// Atomic-free fill: pos = offs[key] + precomputed rank.
// ---------------------------------------------------------------------------
__global__ __launch_bounds__(256) void fill_kernel(
    const int* __restrict__ eu, const int* __restrict__ ei,
    const float* __restrict__ ew,
    const int* __restrict__ offs,
    const int* __restrict__ rank_u, const int* __restrict__ rank_i,
    int2* __restrict__ pairs)
{
    int t = blockIdx.x * 256 + threadIdx.x;
    if (t >= NMEMB) return;
    if (t < NEDGE) {
        int e = t;
        int b = e / E_N;
        int key = eu[e] * 4 + b;
        int pos = offs[key] + rank_u[e];
        pairs[pos] = make_int2(ei[e], __float_as_int(ew[e]));
    } else {
        int e = t - NEDGE;
        int b = e / E_N;
        int key = NKEYU + ei[e] * 4 + b;
        int pos = offs[key] + rank_i[e];
        pairs[pos] = make_int2(eu[e], __float_as_int(ew[e]));
    }
}

// ---------------------------------------------------------------------------
// Fused gather: one wave per destination row; lane owns 2 dims (1 uint of
// 2 bf16). 4 behavior buckets in lockstep, x2-unrolled: 8 memberships in
// flight (8 aligned int2 pair loads + 8 T-row loads). Dead/odd-tail slots
// clamp to the PREVIOUS valid index -> re-read same pair & same T row
// (L2 hits, zero extra HBM). All wave-uniform control in SGPRs via
// readfirstlane. NT stores keep L2/L3 for the bf16 row pool.
// ---------------------------------------------------------------------------
__global__ __launch_bounds__(256) void gather_kernel(
    const unsigned int* __restrict__ tA, const unsigned int* __restrict__ tB,
    const int2* __restrict__ pairs, const int* __restrict__ offs,
    float* __restrict__ single_u, float* __restrict__ multi_u,
    float* __restrict__ single_i, float* __restrict__ multi_i,
    const float* __restrict__ alpha_p)
{
    int rg = blockIdx.x * 4 + (threadIdx.x >> 6);
    if (rg >= U_N + I_N) return;
    bool uside = rg < U_N;
    int r = uside ? rg : rg - U_N;
    const unsigned int* T = uside ? tA : tB;
    float* single  = uside ? single_u : single_i;
    float* multi   = uside ? multi_u : multi_i;
    int N  = uside ? U_N : I_N;
    int k0 = uside ? r * 4 : NKEYU + r * 4;

    float alpha = alpha_p[0];
    int lane = threadIdx.x & 63;

    int o0 = __builtin_amdgcn_readfirstlane(offs[k0]);
    int o1 = __builtin_amdgcn_readfirstlane(offs[k0 + 1]);
    int o2 = __builtin_amdgcn_readfirstlane(offs[k0 + 2]);
    int o3 = __builtin_amdgcn_readfirstlane(offs[k0 + 3]);
    int o4 = __builtin_amdgcn_readfirstlane(offs[k0 + 4]);
    int p0 = o0, p1 = o1, p2 = o2, p3 = o3;

    float ax0 = 0.f, ay0 = 0.f, ax1 = 0.f, ay1 = 0.f;
    float ax2 = 0.f, ay2 = 0.f, ax3 = 0.f, ay3 = 0.f;

    while ((p0 < o1) | (p1 < o2) | (p2 < o3) | (p3 < o4)) {
        int a0 = p0 < o1, b0 = (p0 + 1) < o1;
        int a1 = p1 < o2, b1 = (p1 + 1) < o2;
        int a2 = p2 < o3, b2 = (p2 + 1) < o3;
        int a3 = p3 < o4, b3 = (p3 + 1) < o4;
        // a-slot clamps to bucket-group start; b-slot clamps to a-slot
        // (same pair, same T row -> pure cache hits, no wasted HBM).
        int i0a = a0 ? p0 : o0;         int i0b = b0 ? (p0 + 1) : i0a;
        int i1a = a1 ? p1 : o0;         int i1b = b1 ? (p1 + 1) : i1a;
        int i2a = a2 ? p2 : o0;         int i2b = b2 ? (p2 + 1) : i2a;
        int i3a = a3 ? p3 : o0;         int i3b = b3 ? (p3 + 1) : i3a;
        int2 q0a = pairs[i0a], q0b = pairs[i0b];
        int2 q1a = pairs[i1a], q1b = pairs[i1b];
        int2 q2a = pairs[i2a], q2b = pairs[i2b];
        int2 q3a = pairs[i3a], q3b = pairs[i3b];
        int sx0a = __builtin_amdgcn_readfirstlane(q0a.x);
        int sw0a = __builtin_amdgcn_readfirstlane(q0a.y);
        int sx0b = __builtin_amdgcn_readfirstlane(q0b.x);
        int sw0b = __builtin_amdgcn_readfirstlane(q0b.y);
        int sx1a = __builtin_amdgcn_readfirstlane(q1a.x);
        int sw1a = __builtin_amdgcn_readfirstlane(q1a.y);
        int sx1b = __builtin_amdgcn_readfirstlane(q1b.x);
        int sw1b = __builtin_amdgcn_readfirstlane(q1b.y);
        int sx2a = __builtin_amdgcn_readfirstlane(q2a.x);
        int sw2a = __builtin_amdgcn_readfirstlane(q2a.y);
        int sx2b = __builtin_amdgcn_readfirstlane(q2b.x);
        int sw2b = __builtin_amdgcn_readfirstlane(q2b.y);
        int sx3a = __builtin_amdgcn_readfirstlane(q3a.x);
        int sw3a = __builtin_amdgcn_readfirstlane(q3a.y);
        int sx3b = __builtin_amdgcn_readfirstlane(q3b.x);
        int sw3b = __builtin_amdgcn_readfirstlane(q3b.y);
        unsigned int d0a = T[(size_t)sx0a * (D_N / 2) + lane];
        unsigned int d0b = T[(size_t)sx0b * (D_N / 2) + lane];
        unsigned int d1a = T[(size_t)sx1a * (D_N / 2) + lane];
        unsigned int d1b = T[(size_t)sx1b * (D_N / 2) + lane];
        unsigned int d2a = T[(size_t)sx2a * (D_N / 2) + lane];
        unsigned int d2b = T[(size_t)sx2b * (D_N / 2) + lane];
        unsigned int d3a = T[(size_t)sx3a * (D_N / 2) + lane];
        unsigned int d3b = T[(size_t)sx3b * (D_N / 2) + lane];
        float w0a = a0 ? __int_as_float(sw0a) : 0.f;
        float w0b = b0 ? __int_as_float(sw0b) : 0.f;
        float w1a = a1 ? __int_as_float(sw1a) : 0.f;
        float w1b = b1 ? __int_as_float(sw1b) : 0.f;
        float w2a = a2 ? __int_as_float(sw2a) : 0.f;
        float w2b = b2 ? __int_as_float(sw2b) : 0.f;
        float w3a = a3 ? __int_as_float(sw3a) : 0.f;
        float w3b = b3 ? __int_as_float(sw3b) : 0.f;
        ax0 += w0a * __uint_as_float(d0a << 16)
             + w0b * __uint_as_float(d0b << 16);
        ay0 += w0a * __uint_as_float(d0a & 0xFFFF0000u)
             + w0b * __uint_as_float(d0b & 0xFFFF0000u);
        ax1 += w1a * __uint_as_float(d1a << 16)
             + w1b * __uint_as_float(d1b << 16);
        ay1 += w1a * __uint_as_float(d1a & 0xFFFF0000u)
             + w1b * __uint_as_float(d1b & 0xFFFF0000u);
        ax2 += w2a * __uint_as_float(d2a << 16)
             + w2b * __uint_as_float(d2b << 16);
        ay2 += w2a * __uint_as_float(d2a & 0xFFFF0000u)
             + w2b * __uint_as_float(d2b & 0xFFFF0000u);
        ax3 += w3a * __uint_as_float(d3a << 16)
             + w3b * __uint_as_float(d3b << 16);
        ay3 += w3a * __uint_as_float(d3a & 0xFFFF0000u)
             + w3b * __uint_as_float(d3b & 0xFFFF0000u);
        p0 += a0 + b0; p1 += a1 + b1; p2 += a2 + b2; p3 += a3 + b3;
    }

    float mx = 0.25f * (ax0 + ax1 + ax2 + ax3);
    float my = 0.25f * (ay0 + ay1 + ay2 + ay3);

    f32x2 o;
    o.x = ax0 >= 0.f ? ax0 : alpha * ax0;
    o.y = ay0 >= 0.f ? ay0 : alpha * ay0;
    __builtin_nontemporal_store(o, reinterpret_cast<f32x2*>(
        single + ((size_t)0 * N + r) * D_N + lane * 2));
    o.x = ax1 >= 0.f ? ax1 : alpha * ax1;
    o.y = ay1 >= 0.f ? ay1 : alpha * ay1;
    __builtin_nontemporal_store(o, reinterpret_cast<f32x2*>(
        single + ((size_t)1 * N + r) * D_N + lane * 2));
    o.x = ax2 >= 0.f ? ax2 : alpha * ax2;
    o.y = ay2 >= 0.f ? ay2 : alpha * ay2;
    __builtin_nontemporal_store(o, reinterpret_cast<f32x2*>(
        single + ((size_t)2 * N + r) * D_N + lane * 2));
    o.x = ax3 >= 0.f ? ax3 : alpha * ax3;
    o.y = ay3 >= 0.f ? ay3 : alpha * ay3;
    __builtin_nontemporal_store(o, reinterpret_cast<f32x2*>(
        single + ((size_t)3 * N + r) * D_N + lane * 2));

    o.x = mx >= 0.f ? mx : alpha * mx;
    o.y = my >= 0.f ? my : alpha * my;
    __builtin_nontemporal_store(o, reinterpret_cast<f32x2*>(
        multi + (size_t)r * D_N + lane * 2));
}

extern "C" void kernel_launch(void* const* d_in, const int* in_sizes, int n_in,
                              void* d_out, int out_size, void* d_ws, size_t ws_size,
                              hipStream_t stream) {
    const float* user_emb = (const float*)d_in[0];
    const float* item_emb = (const float*)d_in[1];
    const int*   eu       = (const int*)d_in[2];
    const int*   ei       = (const int*)d_in[3];
    const float* ew       = (const float*)d_in[4];
    const float* u_w      = (const float*)d_in[5];
    const float* i_w      = (const float*)d_in[6];
    const float* alpha    = (const float*)d_in[7];

    float* out      = (float*)d_out;
    float* multi_u  = out;                                      // [U][D]
    float* multi_i  = out + (size_t)U_N * D_N;                  // [I][D]
    float* single_u = out + (size_t)(U_N + I_N) * D_N;          // [B][U][D]
    float* single_i = single_u + (size_t)B_N * U_N * D_N;       // [B][I][D]

    // ranks live in multi_i's slot (consumed by fill; gather writes after).
    int* rank_u = (int*)multi_i;                                // 8 MB
    int* rank_i = rank_u + NEDGE;                               // 8 MB

    // d_ws: offs | bsum | pairs(+2 sentinels) | tA(bf16) | tB(bf16) (~73 MB)
    int*  offs  = (int*)d_ws;                                   // NKEYS+4
    int*  bsum  = offs + (NKEYS + 4);                           // 512
    int2* pairs = (int2*)((char*)d_ws + ((((NKEYS + 4 + 512) * 4) + 255) & ~255));
    unsigned int* tA = (unsigned int*)(pairs + NMEMB + 2);      // [I][64] 12.8 MB
    unsigned int* tB = tA + (size_t)I_N * (D_N / 2);            // [U][64] 25.6 MB

    transform2_kernel<<<TBI + TBU + ZB, 256, 0, stream>>>(
        item_emb, user_emb, u_w, i_w, tA, tB, (int4*)offs, pairs + NMEMB);
    count_kernel<<<CB, 256, 0, stream>>>(eu, ei, offs, rank_u, rank_i);
    scan1_kernel<<<SNBLK, 256, 0, stream>>>(offs, bsum);
    scan2_kernel<<<1, 512, 0, stream>>>(bsum, offs);
    scan3_kernel<<<SNBLK, 256, 0, stream>>>(offs, bsum);
    fill_kernel<<<CB, 256, 0, stream>>>(eu, ei, ew, offs,
                                        rank_u, rank_i, pairs);
    gather_kernel<<<(U_N + I_N + 3) / 4, 256, 0, stream>>>(
        tA, tB, pairs, offs,
        single_u, multi_u, single_i, multi_i, alpha);
}

// Round 16
// 547.804 us; speedup vs baseline: 1.1120x; 1.0865x over previous
//
#include <hip/hip_runtime.h>

#define U_N 100000
#define I_N 50000
#define D_N 128
#define B_N 4
#define E_N 500000
#define NEDGE (B_N * E_N)            // 2,000,000
#define NKEYU (4 * U_N)              // keys u*4+b
#define NKEYS (NKEYU + 4 * I_N)      // 600,000
#define NMEMB (2 * NEDGE)            // 4,000,000
#define SCHUNK 2048
#define SNBLK ((NKEYS + SCHUNK - 1) / SCHUNK)   // 293
#define TBI ((I_N + 31) / 32)        // transform blocks (item side)
#define TBU ((U_N + 31) / 32)        // transform blocks (user side)
#define CB  ((NMEMB + 255) / 256)    // count/fill blocks
#define NZ4 ((NKEYS + 4) / 4)        // int4 count for offs zeroing
#define ZB  ((NZ4 + 255) / 256)      // zero-role blocks

#define SRC_MASK 0x1FFFFu            // low 17 bits: source row index
#define W_MASK   0xFFFE0000u         // high 15 bits: float top bits of weight

typedef float f32x2 __attribute__((ext_vector_type(2)));

// round-to-nearest-even-ish bf16 pack of two floats -> uint (lo=a, hi=b)
__device__ inline unsigned int pack_bf16(float a, float b) {
    unsigned int ua = __float_as_uint(a);
    ua += 0x7FFFu + ((ua >> 16) & 1u);
    unsigned int ub = __float_as_uint(b);
    ub += 0x7FFFu + ((ub >> 16) & 1u);
    return (ua >> 16) | (ub & 0xFFFF0000u);
}

// ---------------------------------------------------------------------------
// Fused: tA = item_emb @ u_w (bf16), tB = user_emb @ i_w (bf16) with
// LDS-staged W, plus zero-role blocks clearing offs[].
// (transform+count fusion rejected twice: r12 no-LDS L2 storm, r14 LDS
//  occupancy tax on count-role blocks. Keep roles in separate kernels.)
// ---------------------------------------------------------------------------
__global__ __launch_bounds__(256) void transform2_kernel(
    const float* __restrict__ item_emb, const float* __restrict__ user_emb,
    const float* __restrict__ u_w, const float* __restrict__ i_w,
    unsigned int* __restrict__ tA, unsigned int* __restrict__ tB,
    int4* __restrict__ offs4)
{
    __shared__ float wlds[D_N][D_N];

    const float* X; const float* W; unsigned int* Y; int N; int blk;
    if (blockIdx.x < TBI) {
        X = item_emb; W = u_w; Y = tA; N = I_N; blk = blockIdx.x;
    } else if (blockIdx.x < TBI + TBU) {
        X = user_emb; W = i_w; Y = tB; N = U_N; blk = blockIdx.x - TBI;
    } else {
        int t = (blockIdx.x - TBI - TBU) * 256 + threadIdx.x;
        if (t < NZ4) offs4[t] = make_int4(0, 0, 0, 0);
        return;
    }

    for (int idx = threadIdx.x; idx < D_N * D_N / 4; idx += 256)
        reinterpret_cast<float4*>(&wlds[0][0])[idx] =
            reinterpret_cast<const float4*>(W)[idx];
    __syncthreads();

    int rr = threadIdx.x & 31;
    int cg = threadIdx.x >> 5;
    int c0 = cg * 16;
    int r  = blk * 32 + rr;
    bool valid = (r < N);
    int rc = valid ? r : (N - 1);
    const float* xrow = X + (size_t)rc * D_N;

    float4 acc[4];
    #pragma unroll
    for (int c = 0; c < 4; ++c) acc[c] = make_float4(0.f, 0.f, 0.f, 0.f);

    for (int k4 = 0; k4 < D_N / 4; ++k4) {
        float4 a = *reinterpret_cast<const float4*>(xrow + k4 * 4);
        #pragma unroll
        for (int kk = 0; kk < 4; ++kk) {
            float ak = (kk == 0) ? a.x : (kk == 1) ? a.y : (kk == 2) ? a.z : a.w;
            #pragma unroll
            for (int c = 0; c < 4; ++c) {
                const float4 wv = *reinterpret_cast<const float4*>(
                    &wlds[k4 * 4 + kk][c0 + c * 4]);
                acc[c].x += ak * wv.x;
                acc[c].y += ak * wv.y;
                acc[c].z += ak * wv.z;
                acc[c].w += ak * wv.w;
            }
        }
    }
    if (valid) {
        unsigned int* yrow = Y + (size_t)r * (D_N / 2) + c0 / 2;
        #pragma unroll
        for (int c = 0; c < 4; ++c) {
            yrow[2 * c]     = pack_bf16(acc[c].x, acc[c].y);
            yrow[2 * c + 1] = pack_bf16(acc[c].z, acc[c].w);
        }
    }
}

// ---------------------------------------------------------------------------
// Count + rank: one membership per thread; atomic return value = rank.
// ---------------------------------------------------------------------------
__global__ __launch_bounds__(256) void count_kernel(
    const int* __restrict__ eu, const int* __restrict__ ei,
    int* __restrict__ offs, int* __restrict__ rank_u, int* __restrict__ rank_i)
{
    int t = blockIdx.x * 256 + threadIdx.x;
    if (t >= NMEMB) return;
    if (t < NEDGE) {
        int e = t;
        int key = eu[e] * 4 + e / E_N;
        rank_u[e] = atomicAdd(&offs[key], 1);
    } else {
        int e = t - NEDGE;
        int key = NKEYU + ei[e] * 4 + e / E_N;
        rank_i[e] = atomicAdd(&offs[key], 1);
    }
}

// ---------------------------------------------------------------------------
// In-place hierarchical exclusive scan over offs[NKEYS].
// ---------------------------------------------------------------------------
__global__ __launch_bounds__(256) void scan1_kernel(
    int* __restrict__ offs, int* __restrict__ bsum)
{
    __shared__ int s[256];
    int base = blockIdx.x * SCHUNK + threadIdx.x * 8;
    int v[8]; int tsum = 0;
    #pragma unroll
    for (int j = 0; j < 8; ++j) {
        int idx = base + j;
        v[j] = (idx < NKEYS) ? offs[idx] : 0;
        tsum += v[j];
    }
    s[threadIdx.x] = tsum; __syncthreads();
    for (int off = 1; off < 256; off <<= 1) {
        int t = (threadIdx.x >= off) ? s[threadIdx.x - off] : 0;
        __syncthreads(); s[threadIdx.x] += t; __syncthreads();
    }
    int excl = s[threadIdx.x] - tsum;
    if (threadIdx.x == 255) bsum[blockIdx.x] = s[255];
    int run = excl;
    #pragma unroll
    for (int j = 0; j < 8; ++j) {
        int idx = base + j;
        if (idx < NKEYS) offs[idx] = run;
        run += v[j];
    }
}

__global__ __launch_bounds__(512) void scan2_kernel(int* __restrict__ bsum,
                                                    int* __restrict__ offs)
{
    __shared__ int s[512];
    int v = (threadIdx.x < SNBLK) ? bsum[threadIdx.x] : 0;
    s[threadIdx.x] = v; __syncthreads();
    for (int off = 1; off < 512; off <<= 1) {
        int t = (threadIdx.x >= off) ? s[threadIdx.x - off] : 0;
        __syncthreads(); s[threadIdx.x] += t; __syncthreads();
    }
    if (threadIdx.x < SNBLK) bsum[threadIdx.x] = s[threadIdx.x] - v;
    if (threadIdx.x == 511) offs[NKEYS] = s[511];
}

__global__ __launch_bounds__(256) void scan3_kernel(int* __restrict__ offs,
                                                    const int* __restrict__ bsum)
{
    int add = bsum[blockIdx.x];
    int base = blockIdx.x * SCHUNK + threadIdx.x * 8;
    #pragma unroll
    for (int j = 0; j < 8; ++j) {
        int idx = base + j;
        if (idx < NKEYS) offs[idx] += add;
    }
}

// ---------------------------------------------------------------------------
// Atomic-free fill: pos = offs[key] + precomputed rank. Pair packed to 4 B:
// src (low 17 bits) | rounded float-top-15 weight bits (high 15).
// Halves the pairs array (16 MB) -> ~half the scattered-store line churn.
// ---------------------------------------------------------------------------
__global__ __launch_bounds__(256) void fill_kernel(
    const int* __restrict__ eu, const int* __restrict__ ei,
    const float* __restrict__ ew,
    const int* __restrict__ offs,
    const int* __restrict__ rank_u, const int* __restrict__ rank_i,
    unsigned int* __restrict__ pairs)
{
    int t = blockIdx.x * 256 + threadIdx.x;
    if (t >= NMEMB) return;
    if (t < NEDGE) {
        int e = t;
        int b = e / E_N;
        int key = eu[e] * 4 + b;
        int pos = offs[key] + rank_u[e];
        unsigned int wb = __float_as_uint(ew[e]) + 0x10000u;  // round bit 17
        pairs[pos] = (wb & W_MASK) | (unsigned int)ei[e];
    } else {
        int e = t - NEDGE;
        int b = e / E_N;
        int key = NKEYU + ei[e] * 4 + b;
        int pos = offs[key] + rank_i[e];
        unsigned int wb = __float_as_uint(ew[e]) + 0x10000u;
        pairs[pos] = (wb & W_MASK) | (unsigned int)eu[e];
    }
}

// ---------------------------------------------------------------------------
// Fused gather: one wave per destination row; lane owns 2 dims (1 uint of
// 2 bf16). 4 behavior buckets in lockstep, x2-unrolled: 8 memberships in
// flight (8 NT dword pair loads + 8 T-row loads). Packed 4B pairs: one
// readfirstlane per membership, scalar AND decode. Dead slots clamp to a
// previously-valid index (same pair, same T row -> cache hits). NT loads
// for the pair stream and NT stores for outputs keep L2 for the row pool.
// ---------------------------------------------------------------------------
__global__ __launch_bounds__(256) void gather_kernel(
    const unsigned int* __restrict__ tA, const unsigned int* __restrict__ tB,
    const unsigned int* __restrict__ pairs, const int* __restrict__ offs,
    float* __restrict__ single_u, float* __restrict__ multi_u,
    float* __restrict__ single_i, float* __restrict__ multi_i,
    const float* __restrict__ alpha_p)
{
    int rg = blockIdx.x * 4 + (threadIdx.x >> 6);
    if (rg >= U_N + I_N) return;
    bool uside = rg < U_N;
    int r = uside ? rg : rg - U_N;
    const unsigned int* T = uside ? tA : tB;
    float* single  = uside ? single_u : single_i;
    float* multi   = uside ? multi_u : multi_i;
    int N  = uside ? U_N : I_N;
    int k0 = uside ? r * 4 : NKEYU + r * 4;

    float alpha = alpha_p[0];
    int lane = threadIdx.x & 63;

    int o0 = __builtin_amdgcn_readfirstlane(offs[k0]);
    int o1 = __builtin_amdgcn_readfirstlane(offs[k0 + 1]);
    int o2 = __builtin_amdgcn_readfirstlane(offs[k0 + 2]);
    int o3 = __builtin_amdgcn_readfirstlane(offs[k0 + 3]);
    int o4 = __builtin_amdgcn_readfirstlane(offs[k0 + 4]);
    int p0 = o0, p1 = o1, p2 = o2, p3 = o3;

    float ax0 = 0.f, ay0 = 0.f, ax1 = 0.f, ay1 = 0.f;
    float ax2 = 0.f, ay2 = 0.f, ax3 = 0.f, ay3 = 0.f;

    while ((p0 < o1) | (p1 < o2) | (p2 < o3) | (p3 < o4)) {
        int a0 = p0 < o1, b0 = (p0 + 1) < o1;
        int a1 = p1 < o2, b1 = (p1 + 1) < o2;
        int a2 = p2 < o3, b2 = (p2 + 1) < o3;
        int a3 = p3 < o4, b3 = (p3 + 1) < o4;
        int i0a = a0 ? p0 : o0;         int i0b = b0 ? (p0 + 1) : i0a;
        int i1a = a1 ? p1 : o0;         int i1b = b1 ? (p1 + 1) : i1a;
        int i2a = a2 ? p2 : o0;         int i2b = b2 ? (p2 + 1) : i2a;
        int i3a = a3 ? p3 : o0;         int i3b = b3 ? (p3 + 1) : i3a;
        unsigned int s0a = __builtin_amdgcn_readfirstlane(
            __builtin_nontemporal_load(pairs + i0a));
        unsigned int s0b = __builtin_amdgcn_readfirstlane(
            __builtin_nontemporal_load(pairs + i0b));
        unsigned int s1a = __builtin_amdgcn_readfirstlane(
            __builtin_nontemporal_load(pairs + i1a));
        unsigned int s1b = __builtin_amdgcn_readfirstlane(
            __builtin_nontemporal_load(pairs + i1b));
        unsigned int s2a = __builtin_amdgcn_readfirstlane(
            __builtin_nontemporal_load(pairs + i2a));
        unsigned int s2b = __builtin_amdgcn_readfirstlane(
            __builtin_nontemporal_load(pairs + i2b));
        unsigned int s3a = __builtin_amdgcn_readfirstlane(
            __builtin_nontemporal_load(pairs + i3a));
        unsigned int s3b = __builtin_amdgcn_readfirstlane(
            __builtin_nontemporal_load(pairs + i3b));
        unsigned int d0a = T[(size_t)(s0a & SRC_MASK) * (D_N / 2) + lane];
        unsigned int d0b = T[(size_t)(s0b & SRC_MASK) * (D_N / 2) + lane];
        unsigned int d1a = T[(size_t)(s1a & SRC_MASK) * (D_N / 2) + lane];
        unsigned int d1b = T[(size_t)(s1b & SRC_MASK) * (D_N / 2) + lane];
        unsigned int d2a = T[(size_t)(s2a & SRC_MASK) * (D_N / 2) + lane];
        unsigned int d2b = T[(size_t)(s2b & SRC_MASK) * (D_N / 2) + lane];
        unsigned int d3a = T[(size_t)(s3a & SRC_MASK) * (D_N / 2) + lane];
        unsigned int d3b = T[(size_t)(s3b & SRC_MASK) * (D_N / 2) + lane];
        float w0a = a0 ? __uint_as_float(s0a & W_MASK) : 0.f;
        float w0b = b0 ? __uint_as_float(s0b & W_MASK) : 0.f;
        float w1a = a1 ? __uint_as_float(s1a & W_MASK) : 0.f;
        float w1b = b1 ? __uint_as_float(s1b & W_MASK) : 0.f;
        float w2a = a2 ? __uint_as_float(s2a & W_MASK) : 0.f;
        float w2b = b2 ? __uint_as_float(s2b & W_MASK) : 0.f;
        float w3a = a3 ? __uint_as_float(s3a & W_MASK) : 0.f;
        float w3b = b3 ? __uint_as_float(s3b & W_MASK) : 0.f;
        ax0 += w0a * __uint_as_float(d0a << 16)
             + w0b * __uint_as_float(d0b << 16);
        ay0 += w0a * __uint_as_float(d0a & 0xFFFF0000u)
             + w0b * __uint_as_float(d0b & 0xFFFF0000u);
        ax1 += w1a * __uint_as_float(d1a << 16)
             + w1b * __uint_as_float(d1b << 16);
        ay1 += w1a * __uint_as_float(d1a & 0xFFFF0000u)
             + w1b * __uint_as_float(d1b & 0xFFFF0000u);
        ax2 += w2a * __uint_as_float(d2a << 16)
             + w2b * __uint_as_float(d2b << 16);
        ay2 += w2a * __uint_as_float(d2a & 0xFFFF0000u)
             + w2b * __uint_as_float(d2b & 0xFFFF0000u);
        ax3 += w3a * __uint_as_float(d3a << 16)
             + w3b * __uint_as_float(d3b << 16);
        ay3 += w3a * __uint_as_float(d3a & 0xFFFF0000u)
             + w3b * __uint_as_float(d3b & 0xFFFF0000u);
        p0 += a0 + b0; p1 += a1 + b1; p2 += a2 + b2; p3 += a3 + b3;
    }

    float mx = 0.25f * (ax0 + ax1 + ax2 + ax3);
    float my = 0.25f * (ay0 + ay1 + ay2 + ay3);

    f32x2 o;
    o.x = ax0 >= 0.f ? ax0 : alpha * ax0;
    o.y = ay0 >= 0.f ? ay0 : alpha * ay0;
    __builtin_nontemporal_store(o, reinterpret_cast<f32x2*>(
        single + ((size_t)0 * N + r) * D_N + lane * 2));
    o.x = ax1 >= 0.f ? ax1 : alpha * ax1;
    o.y = ay1 >= 0.f ? ay1 : alpha * ay1;
    __builtin_nontemporal_store(o, reinterpret_cast<f32x2*>(
        single + ((size_t)1 * N + r) * D_N + lane * 2));
    o.x = ax2 >= 0.f ? ax2 : alpha * ax2;
    o.y = ay2 >= 0.f ? ay2 : alpha * ay2;
    __builtin_nontemporal_store(o, reinterpret_cast<f32x2*>(
        single + ((size_t)2 * N + r) * D_N + lane * 2));
    o.x = ax3 >= 0.f ? ax3 : alpha * ax3;
    o.y = ay3 >= 0.f ? ay3 : alpha * ay3;
    __builtin_nontemporal_store(o, reinterpret_cast<f32x2*>(
        single + ((size_t)3 * N + r) * D_N + lane * 2));

    o.x = mx >= 0.f ? mx : alpha * mx;
    o.y = my >= 0.f ? my : alpha * my;
    __builtin_nontemporal_store(o, reinterpret_cast<f32x2*>(
        multi + (size_t)r * D_N + lane * 2));
}

extern "C" void kernel_launch(void* const* d_in, const int* in_sizes, int n_in,
                              void* d_out, int out_size, void* d_ws, size_t ws_size,
                              hipStream_t stream) {
    const float* user_emb = (const float*)d_in[0];
    const float* item_emb = (const float*)d_in[1];
    const int*   eu       = (const int*)d_in[2];
    const int*   ei       = (const int*)d_in[3];
    const float* ew       = (const float*)d_in[4];
    const float* u_w      = (const float*)d_in[5];
    const float* i_w      = (const float*)d_in[6];
    const float* alpha    = (const float*)d_in[7];

    float* out      = (float*)d_out;
    float* multi_u  = out;                                      // [U][D]
    float* multi_i  = out + (size_t)U_N * D_N;                  // [I][D]
    float* single_u = out + (size_t)(U_N + I_N) * D_N;          // [B][U][D]
    float* single_i = single_u + (size_t)B_N * U_N * D_N;       // [B][I][D]

    // ranks live in multi_i's slot (consumed by fill; gather writes after).
    int* rank_u = (int*)multi_i;                                // 8 MB
    int* rank_i = rank_u + NEDGE;                               // 8 MB

    // d_ws: offs | bsum | pairs(4B packed) | tA(bf16) | tB(bf16) (~57 MB)
    int*  offs  = (int*)d_ws;                                   // NKEYS+4
    int*  bsum  = offs + (NKEYS + 4);                           // 512
    unsigned int* pairs =
        (unsigned int*)((char*)d_ws + ((((NKEYS + 4 + 512) * 4) + 255) & ~255));
    unsigned int* tA = pairs + NMEMB;                           // [I][64] 12.8 MB
    unsigned int* tB = tA + (size_t)I_N * (D_N / 2);            // [U][64] 25.6 MB

    transform2_kernel<<<TBI + TBU + ZB, 256, 0, stream>>>(
        item_emb, user_emb, u_w, i_w, tA, tB, (int4*)offs);
    count_kernel<<<CB, 256, 0, stream>>>(eu, ei, offs, rank_u, rank_i);
    scan1_kernel<<<SNBLK, 256, 0, stream>>>(offs, bsum);
    scan2_kernel<<<1, 512, 0, stream>>>(bsum, offs);
    scan3_kernel<<<SNBLK, 256, 0, stream>>>(offs, bsum);
    fill_kernel<<<CB, 256, 0, stream>>>(eu, ei, ew, offs,
                                        rank_u, rank_i, pairs);
    gather_kernel<<<(U_N + I_N + 3) / 4, 256, 0, stream>>>(
        tA, tB, pairs, offs,
        single_u, multi_u, single_i, multi_i, alpha);
}

// Round 17
// 545.526 us; speedup vs baseline: 1.1166x; 1.0042x over previous
//
#include <hip/hip_runtime.h>

#define U_N 100000
#define I_N 50000
#define D_N 128
#define B_N 4
#define E_N 500000
#define NEDGE (B_N * E_N)            // 2,000,000
#define NKEYU (4 * U_N)              // keys u*4+b
#define NKEYS (NKEYU + 4 * I_N)      // 600,000
#define NMEMB (2 * NEDGE)            // 4,000,000
#define SCHUNK 2048
#define SNBLK ((NKEYS + SCHUNK - 1) / SCHUNK)   // 293
#define TBI ((I_N + 31) / 32)        // transform blocks (item side)
#define TBU ((U_N + 31) / 32)        // transform blocks (user side)
#define CB  ((NMEMB + 255) / 256)    // count/fill blocks
#define NZ4 ((NKEYS + 4) / 4)        // int4 count for offs zeroing
#define ZB  ((NZ4 + 255) / 256)      // zero-role blocks

#define SRC_MASK 0x1FFFFu            // low 17 bits: source row index
#define W_MASK   0xFFFE0000u         // high 15 bits: float top bits of weight

typedef float f32x2 __attribute__((ext_vector_type(2)));

// round-to-nearest-even-ish bf16 pack of two floats -> uint (lo=a, hi=b)
__device__ inline unsigned int pack_bf16(float a, float b) {
    unsigned int ua = __float_as_uint(a);
    ua += 0x7FFFu + ((ua >> 16) & 1u);
    unsigned int ub = __float_as_uint(b);
    ub += 0x7FFFu + ((ub >> 16) & 1u);
    return (ua >> 16) | (ub & 0xFFFF0000u);
}

// ---------------------------------------------------------------------------
// Fused: tA = item_emb @ u_w (bf16), tB = user_emb @ i_w (bf16) with
// LDS-staged W, plus zero-role blocks clearing offs[].
// (transform+count fusion rejected twice: r12 no-LDS L2 storm, r14 LDS
//  occupancy tax on count-role blocks. Keep roles in separate kernels.)
// ---------------------------------------------------------------------------
__global__ __launch_bounds__(256) void transform2_kernel(
    const float* __restrict__ item_emb, const float* __restrict__ user_emb,
    const float* __restrict__ u_w, const float* __restrict__ i_w,
    unsigned int* __restrict__ tA, unsigned int* __restrict__ tB,
    int4* __restrict__ offs4)
{
    __shared__ float wlds[D_N][D_N];

    const float* X; const float* W; unsigned int* Y; int N; int blk;
    if (blockIdx.x < TBI) {
        X = item_emb; W = u_w; Y = tA; N = I_N; blk = blockIdx.x;
    } else if (blockIdx.x < TBI + TBU) {
        X = user_emb; W = i_w; Y = tB; N = U_N; blk = blockIdx.x - TBI;
    } else {
        int t = (blockIdx.x - TBI - TBU) * 256 + threadIdx.x;
        if (t < NZ4) offs4[t] = make_int4(0, 0, 0, 0);
        return;
    }

    for (int idx = threadIdx.x; idx < D_N * D_N / 4; idx += 256)
        reinterpret_cast<float4*>(&wlds[0][0])[idx] =
            reinterpret_cast<const float4*>(W)[idx];
    __syncthreads();

    int rr = threadIdx.x & 31;
    int cg = threadIdx.x >> 5;
    int c0 = cg * 16;
    int r  = blk * 32 + rr;
    bool valid = (r < N);
    int rc = valid ? r : (N - 1);
    const float* xrow = X + (size_t)rc * D_N;

    float4 acc[4];
    #pragma unroll
    for (int c = 0; c < 4; ++c) acc[c] = make_float4(0.f, 0.f, 0.f, 0.f);

    for (int k4 = 0; k4 < D_N / 4; ++k4) {
        float4 a = *reinterpret_cast<const float4*>(xrow + k4 * 4);
        #pragma unroll
        for (int kk = 0; kk < 4; ++kk) {
            float ak = (kk == 0) ? a.x : (kk == 1) ? a.y : (kk == 2) ? a.z : a.w;
            #pragma unroll
            for (int c = 0; c < 4; ++c) {
                const float4 wv = *reinterpret_cast<const float4*>(
                    &wlds[k4 * 4 + kk][c0 + c * 4]);
                acc[c].x += ak * wv.x;
                acc[c].y += ak * wv.y;
                acc[c].z += ak * wv.z;
                acc[c].w += ak * wv.w;
            }
        }
    }
    if (valid) {
        unsigned int* yrow = Y + (size_t)r * (D_N / 2) + c0 / 2;
        #pragma unroll
        for (int c = 0; c < 4; ++c) {
            yrow[2 * c]     = pack_bf16(acc[c].x, acc[c].y);
            yrow[2 * c + 1] = pack_bf16(acc[c].z, acc[c].w);
        }
    }
}

// ---------------------------------------------------------------------------
// Count + rank: one membership per thread; atomic return value = rank.
// ---------------------------------------------------------------------------
__global__ __launch_bounds__(256) void count_kernel(
    const int* __restrict__ eu, const int* __restrict__ ei,
    int* __restrict__ offs, int* __restrict__ rank_u, int* __restrict__ rank_i)
{
    int t = blockIdx.x * 256 + threadIdx.x;
    if (t >= NMEMB) return;
    if (t < NEDGE) {
        int e = t;
        int key = eu[e] * 4 + e / E_N;
        rank_u[e] = atomicAdd(&offs[key], 1);
    } else {
        int e = t - NEDGE;
        int key = NKEYU + ei[e] * 4 + e / E_N;
        rank_i[e] = atomicAdd(&offs[key], 1);
    }
}

// ---------------------------------------------------------------------------
// In-place hierarchical exclusive scan over offs[NKEYS].
// ---------------------------------------------------------------------------
__global__ __launch_bounds__(256) void scan1_kernel(
    int* __restrict__ offs, int* __restrict__ bsum)
{
    __shared__ int s[256];
    int base = blockIdx.x * SCHUNK + threadIdx.x * 8;
    int v[8]; int tsum = 0;
    #pragma unroll
    for (int j = 0; j < 8; ++j) {
        int idx = base + j;
        v[j] = (idx < NKEYS) ? offs[idx] : 0;
        tsum += v[j];
    }
    s[threadIdx.x] = tsum; __syncthreads();
    for (int off = 1; off < 256; off <<= 1) {
        int t = (threadIdx.x >= off) ? s[threadIdx.x - off] : 0;
        __syncthreads(); s[threadIdx.x] += t; __syncthreads();
    }
    int excl = s[threadIdx.x] - tsum;
    if (threadIdx.x == 255) bsum[blockIdx.x] = s[255];
    int run = excl;
    #pragma unroll
    for (int j = 0; j < 8; ++j) {
        int idx = base + j;
        if (idx < NKEYS) offs[idx] = run;
        run += v[j];
    }
}

__global__ __launch_bounds__(512) void scan2_kernel(int* __restrict__ bsum,
                                                    int* __restrict__ offs)
{
    __shared__ int s[512];
    int v = (threadIdx.x < SNBLK) ? bsum[threadIdx.x] : 0;
    s[threadIdx.x] = v; __syncthreads();
    for (int off = 1; off < 512; off <<= 1) {
        int t = (threadIdx.x >= off) ? s[threadIdx.x - off] : 0;
        __syncthreads(); s[threadIdx.x] += t; __syncthreads();
    }
    if (threadIdx.x < SNBLK) bsum[threadIdx.x] = s[threadIdx.x] - v;
    if (threadIdx.x == 511) offs[NKEYS] = s[511];
}

__global__ __launch_bounds__(256) void scan3_kernel(int* __restrict__ offs,
                                                    const int* __restrict__ bsum)
{
    int add = bsum[blockIdx.x];
    int base = blockIdx.x * SCHUNK + threadIdx.x * 8;
    #pragma unroll
    for (int j = 0; j < 8; ++j) {
        int idx = base + j;
        if (idx < NKEYS) offs[idx] += add;
    }
}

// ---------------------------------------------------------------------------
// Atomic-free fill: pos = offs[key] + precomputed rank. Pair packed to 4 B:
// src (low 17 bits) | rounded float-top-15 weight bits (high 15).
// ---------------------------------------------------------------------------
__global__ __launch_bounds__(256) void fill_kernel(
    const int* __restrict__ eu, const int* __restrict__ ei,
    const float* __restrict__ ew,
    const int* __restrict__ offs,
    const int* __restrict__ rank_u, const int* __restrict__ rank_i,
    unsigned int* __restrict__ pairs)
{
    int t = blockIdx.x * 256 + threadIdx.x;
    if (t >= NMEMB) return;
    if (t < NEDGE) {
        int e = t;
        int b = e / E_N;
        int key = eu[e] * 4 + b;
        int pos = offs[key] + rank_u[e];
        unsigned int wb = __float_as_uint(ew[e]) + 0x10000u;  // round bit 17
        pairs[pos] = (wb & W_MASK) | (unsigned int)ei[e];
    } else {
        int e = t - NEDGE;
        int b = e / E_N;
        int key = NKEYU + ei[e] * 4 + b;
        int pos = offs[key] + rank_i[e];
        unsigned int wb = __float_as_uint(ew[e]) + 0x10000u;
        pairs[pos] = (wb & W_MASK) | (unsigned int)eu[e];
    }
}

// ---------------------------------------------------------------------------
// Gather (one side per dispatch): one wave per destination row; lane owns
// 2 dims (1 uint of 2 bf16). 4 behavior buckets in lockstep, x2-unrolled:
// 8 memberships in flight. Pair loads are wave-uniform (SGPR pointers,
// readfirstlane'd offs) -> compiler emits scalar s_load through the
// constant cache, freeing the vector-memory path for the 8 T-row loads.
// Per-dispatch working set is one side's pool only (tA 12.8 MB / tB
// 25.6 MB) for better per-XCD L2 retention. NT stores for outputs.
// ---------------------------------------------------------------------------
__global__ __launch_bounds__(256) void gather_kernel(
    const unsigned int* __restrict__ T,
    const unsigned int* __restrict__ pairs, const int* __restrict__ offs,
    float* __restrict__ single, float* __restrict__ multi,
    int N, int keybase, const float* __restrict__ alpha_p)
{
    int r = blockIdx.x * 4 + (threadIdx.x >> 6);
    if (r >= N) return;
    int k0 = keybase + r * 4;

    float alpha = alpha_p[0];
    int lane = threadIdx.x & 63;

    int o0 = __builtin_amdgcn_readfirstlane(offs[k0]);
    int o1 = __builtin_amdgcn_readfirstlane(offs[k0 + 1]);
    int o2 = __builtin_amdgcn_readfirstlane(offs[k0 + 2]);
    int o3 = __builtin_amdgcn_readfirstlane(offs[k0 + 3]);
    int o4 = __builtin_amdgcn_readfirstlane(offs[k0 + 4]);
    int p0 = o0, p1 = o1, p2 = o2, p3 = o3;

    float ax0 = 0.f, ay0 = 0.f, ax1 = 0.f, ay1 = 0.f;
    float ax2 = 0.f, ay2 = 0.f, ax3 = 0.f, ay3 = 0.f;

    while ((p0 < o1) | (p1 < o2) | (p2 < o3) | (p3 < o4)) {
        int a0 = p0 < o1, b0 = (p0 + 1) < o1;
        int a1 = p1 < o2, b1 = (p1 + 1) < o2;
        int a2 = p2 < o3, b2 = (p2 + 1) < o3;
        int a3 = p3 < o4, b3 = (p3 + 1) < o4;
        int i0a = a0 ? p0 : o0;         int i0b = b0 ? (p0 + 1) : i0a;
        int i1a = a1 ? p1 : o0;         int i1b = b1 ? (p1 + 1) : i1a;
        int i2a = a2 ? p2 : o0;         int i2b = b2 ? (p2 + 1) : i2a;
        int i3a = a3 ? p3 : o0;         int i3b = b3 ? (p3 + 1) : i3a;
        unsigned int s0a = __builtin_amdgcn_readfirstlane(pairs[i0a]);
        unsigned int s0b = __builtin_amdgcn_readfirstlane(pairs[i0b]);
        unsigned int s1a = __builtin_amdgcn_readfirstlane(pairs[i1a]);
        unsigned int s1b = __builtin_amdgcn_readfirstlane(pairs[i1b]);
        unsigned int s2a = __builtin_amdgcn_readfirstlane(pairs[i2a]);
        unsigned int s2b = __builtin_amdgcn_readfirstlane(pairs[i2b]);
        unsigned int s3a = __builtin_amdgcn_readfirstlane(pairs[i3a]);
        unsigned int s3b = __builtin_amdgcn_readfirstlane(pairs[i3b]);
        unsigned int d0a = T[(size_t)(s0a & SRC_MASK) * (D_N / 2) + lane];
        unsigned int d0b = T[(size_t)(s0b & SRC_MASK) * (D_N / 2) + lane];
        unsigned int d1a = T[(size_t)(s1a & SRC_MASK) * (D_N / 2) + lane];
        unsigned int d1b = T[(size_t)(s1b & SRC_MASK) * (D_N / 2) + lane];
        unsigned int d2a = T[(size_t)(s2a & SRC_MASK) * (D_N / 2) + lane];
        unsigned int d2b = T[(size_t)(s2b & SRC_MASK) * (D_N / 2) + lane];
        unsigned int d3a = T[(size_t)(s3a & SRC_MASK) * (D_N / 2) + lane];
        unsigned int d3b = T[(size_t)(s3b & SRC_MASK) * (D_N / 2) + lane];
        float w0a = a0 ? __uint_as_float(s0a & W_MASK) : 0.f;
        float w0b = b0 ? __uint_as_float(s0b & W_MASK) : 0.f;
        float w1a = a1 ? __uint_as_float(s1a & W_MASK) : 0.f;
        float w1b = b1 ? __uint_as_float(s1b & W_MASK) : 0.f;
        float w2a = a2 ? __uint_as_float(s2a & W_MASK) : 0.f;
        float w2b = b2 ? __uint_as_float(s2b & W_MASK) : 0.f;
        float w3a = a3 ? __uint_as_float(s3a & W_MASK) : 0.f;
        float w3b = b3 ? __uint_as_float(s3b & W_MASK) : 0.f;
        ax0 += w0a * __uint_as_float(d0a << 16)
             + w0b * __uint_as_float(d0b << 16);
        ay0 += w0a * __uint_as_float(d0a & 0xFFFF0000u)
             + w0b * __uint_as_float(d0b & 0xFFFF0000u);
        ax1 += w1a * __uint_as_float(d1a << 16)
             + w1b * __uint_as_float(d1b << 16);
        ay1 += w1a * __uint_as_float(d1a & 0xFFFF0000u)
             + w1b * __uint_as_float(d1b & 0xFFFF0000u);
        ax2 += w2a * __uint_as_float(d2a << 16)
             + w2b * __uint_as_float(d2b << 16);
        ay2 += w2a * __uint_as_float(d2a & 0xFFFF0000u)
             + w2b * __uint_as_float(d2b & 0xFFFF0000u);
        ax3 += w3a * __uint_as_float(d3a << 16)
             + w3b * __uint_as_float(d3b << 16);
        ay3 += w3a * __uint_as_float(d3a & 0xFFFF0000u)
             + w3b * __uint_as_float(d3b & 0xFFFF0000u);
        p0 += a0 + b0; p1 += a1 + b1; p2 += a2 + b2; p3 += a3 + b3;
    }

    float mx = 0.25f * (ax0 + ax1 + ax2 + ax3);
    float my = 0.25f * (ay0 + ay1 + ay2 + ay3);

    f32x2 o;
    o.x = ax0 >= 0.f ? ax0 : alpha * ax0;
    o.y = ay0 >= 0.f ? ay0 : alpha * ay0;
    __builtin_nontemporal_store(o, reinterpret_cast<f32x2*>(
        single + ((size_t)0 * N + r) * D_N + lane * 2));
    o.x = ax1 >= 0.f ? ax1 : alpha * ax1;
    o.y = ay1 >= 0.f ? ay1 : alpha * ay1;
    __builtin_nontemporal_store(o, reinterpret_cast<f32x2*>(
        single + ((size_t)1 * N + r) * D_N + lane * 2));
    o.x = ax2 >= 0.f ? ax2 : alpha * ax2;
    o.y = ay2 >= 0.f ? ay2 : alpha * ay2;
    __builtin_nontemporal_store(o, reinterpret_cast<f32x2*>(
        single + ((size_t)2 * N + r) * D_N + lane * 2));
    o.x = ax3 >= 0.f ? ax3 : alpha * ax3;
    o.y = ay3 >= 0.f ? ay3 : alpha * ay3;
    __builtin_nontemporal_store(o, reinterpret_cast<f32x2*>(
        single + ((size_t)3 * N + r) * D_N + lane * 2));

    o.x = mx >= 0.f ? mx : alpha * mx;
    o.y = my >= 0.f ? my : alpha * my;
    __builtin_nontemporal_store(o, reinterpret_cast<f32x2*>(
        multi + (size_t)r * D_N + lane * 2));
}

extern "C" void kernel_launch(void* const* d_in, const int* in_sizes, int n_in,
                              void* d_out, int out_size, void* d_ws, size_t ws_size,
                              hipStream_t stream) {
    const float* user_emb = (const float*)d_in[0];
    const float* item_emb = (const float*)d_in[1];
    const int*   eu       = (const int*)d_in[2];
    const int*   ei       = (const int*)d_in[3];
    const float* ew       = (const float*)d_in[4];
    const float* u_w      = (const float*)d_in[5];
    const float* i_w      = (const float*)d_in[6];
    const float* alpha    = (const float*)d_in[7];

    float* out      = (float*)d_out;
    float* multi_u  = out;                                      // [U][D]
    float* multi_i  = out + (size_t)U_N * D_N;                  // [I][D]
    float* single_u = out + (size_t)(U_N + I_N) * D_N;          // [B][U][D]
    float* single_i = single_u + (size_t)B_N * U_N * D_N;       // [B][I][D]

    // ranks live in multi_i's slot (consumed by fill; gather writes after).
    int* rank_u = (int*)multi_i;                                // 8 MB
    int* rank_i = rank_u + NEDGE;                               // 8 MB

    // d_ws: offs | bsum | pairs(4B packed) | tA(bf16) | tB(bf16) (~57 MB)
    int*  offs  = (int*)d_ws;                                   // NKEYS+4
    int*  bsum  = offs + (NKEYS + 4);                           // 512
    unsigned int* pairs =
        (unsigned int*)((char*)d_ws + ((((NKEYS + 4 + 512) * 4) + 255) & ~255));
    unsigned int* tA = pairs + NMEMB;                           // [I][64] 12.8 MB
    unsigned int* tB = tA + (size_t)I_N * (D_N / 2);            // [U][64] 25.6 MB

    transform2_kernel<<<TBI + TBU + ZB, 256, 0, stream>>>(
        item_emb, user_emb, u_w, i_w, tA, tB, (int4*)offs);
    count_kernel<<<CB, 256, 0, stream>>>(eu, ei, offs, rank_u, rank_i);
    scan1_kernel<<<SNBLK, 256, 0, stream>>>(offs, bsum);
    scan2_kernel<<<1, 512, 0, stream>>>(bsum, offs);
    scan3_kernel<<<SNBLK, 256, 0, stream>>>(offs, bsum);
    fill_kernel<<<CB, 256, 0, stream>>>(eu, ei, ew, offs,
                                        rank_u, rank_i, pairs);
    // split by side: per-dispatch working set = one bf16 pool only
    gather_kernel<<<(U_N + 3) / 4, 256, 0, stream>>>(
        tA, pairs, offs, single_u, multi_u, U_N, 0, alpha);
    gather_kernel<<<(I_N + 3) / 4, 256, 0, stream>>>(
        tB, pairs, offs, single_i, multi_i, I_N, NKEYU, alpha);
}

// Round 18
// 445.467 us; speedup vs baseline: 1.3675x; 1.2246x over previous
//
#include <hip/hip_runtime.h>

#define U_N 100000
#define I_N 50000
#define D_N 128
#define B_N 4
#define E_N 500000
#define NEDGE (B_N * E_N)            // 2,000,000
#define NKEYU (4 * U_N)              // keys u*4+b
#define NKEYS (NKEYU + 4 * I_N)      // 600,000
#define NMEMB (2 * NEDGE)            // 4,000,000
#define SCHUNK 2048
#define SNBLK ((NKEYS + SCHUNK - 1) / SCHUNK)   // 293
#define CB  ((NMEMB + 255) / 256)    // count/fill blocks
#define NZ4 ((NKEYS + 4) / 4)        // int4 count for offs zeroing
#define ZB  ((NZ4 + 255) / 256)      // zero-role blocks
#define TB2I ((I_N + 63) / 64)       // mfma-transform blocks, item side (782)
#define TB2U ((U_N + 63) / 64)       // mfma-transform blocks, user side (1563)

#define SRC_MASK 0x1FFFFu            // low 17 bits: source row index
#define W_MASK   0xFFFE0000u         // high 15 bits: float top bits of weight

typedef float f32x2 __attribute__((ext_vector_type(2)));
typedef float f32x4 __attribute__((ext_vector_type(4)));
typedef short bf16x8 __attribute__((ext_vector_type(8)));
typedef unsigned int u32x4 __attribute__((ext_vector_type(4)));
typedef unsigned int u32x2 __attribute__((ext_vector_type(2)));

// round-to-nearest-even-ish bf16 pack of two floats -> uint (lo=a, hi=b)
__device__ inline unsigned int pack_bf16(float a, float b) {
    unsigned int ua = __float_as_uint(a);
    ua += 0x7FFFu + ((ua >> 16) & 1u);
    unsigned int ub = __float_as_uint(b);
    ub += 0x7FFFu + ((ub >> 16) & 1u);
    return (ua >> 16) | (ub & 0xFFFF0000u);
}

// ---------------------------------------------------------------------------
// MFMA transform: Y(bf16) = X(fp32->bf16) @ W, via mfma_f32_16x16x32_bf16
// with swapped operands: D[m=c][n=r] = A[m=c][k] * B[k][n=r], where
// A = W^T tile (staged pre-swizzled in 32KB LDS, conflict-free b128 reads)
// and B = X^T tile (8 consecutive fp32 per lane). C/D mapping (verified):
// n = lane&15 (output row), m = (lane>>4)*4 + reg (output col) -> each lane
// holds 4 consecutive output cols = two packed uints, one 8B store.
// One wave per 16 rows, 4 waves/block, one W per block. Zero-role blocks
// clear offs[]. (transform+count fusion rejected twice: r12/r14.)
// ---------------------------------------------------------------------------
__global__ __launch_bounds__(256) void transform_mfma_kernel(
    const float* __restrict__ item_emb, const float* __restrict__ user_emb,
    const float* __restrict__ u_w, const float* __restrict__ i_w,
    unsigned int* __restrict__ tA, unsigned int* __restrict__ tB,
    int4* __restrict__ offs4)
{
    __shared__ short wf[2048 * 8];   // 32 KB: A-frags, [kt(4)][ct(8)][lane(64)][8]

    const float* X; const float* W; unsigned int* Y; int N; int blk;
    if (blockIdx.x < TB2I) {
        X = item_emb; W = u_w; Y = tA; N = I_N; blk = blockIdx.x;
    } else if (blockIdx.x < TB2I + TB2U) {
        X = user_emb; W = i_w; Y = tB; N = U_N; blk = blockIdx.x - TB2I;
    } else {
        int t = (blockIdx.x - TB2I - TB2U) * 256 + threadIdx.x;
        if (t < NZ4) offs4[t] = make_int4(0, 0, 0, 0);
        return;
    }

    // ---- stage W^T fragments into LDS (each W element read exactly once) --
    for (int f = threadIdx.x; f < 2048; f += 256) {
        int kt = f >> 9;             // 0..3
        int l  = f & 63;
        int c  = ((f >> 6) & 7) * 16 + (l & 15);
        int kb = kt * 32 + ((l >> 4) << 3);
        u32x4 q;
        q.x = pack_bf16(W[(kb + 0) * D_N + c], W[(kb + 1) * D_N + c]);
        q.y = pack_bf16(W[(kb + 2) * D_N + c], W[(kb + 3) * D_N + c]);
        q.z = pack_bf16(W[(kb + 4) * D_N + c], W[(kb + 5) * D_N + c]);
        q.w = pack_bf16(W[(kb + 6) * D_N + c], W[(kb + 7) * D_N + c]);
        *reinterpret_cast<u32x4*>(&wf[f * 8]) = q;
    }
    __syncthreads();

    int wave = threadIdx.x >> 6;
    int lane = threadIdx.x & 63;
    int rowbase = blk * 64 + wave * 16;
    if (rowbase >= N) return;        // N % 16 == 0 -> no partial waves

    f32x4 acc[8];
    #pragma unroll
    for (int ct = 0; ct < 8; ++ct) acc[ct] = (f32x4){0.f, 0.f, 0.f, 0.f};

    const float* xr0 = X + (size_t)(rowbase + (lane & 15)) * D_N
                         + ((lane >> 4) << 3);
    #pragma unroll
    for (int kt = 0; kt < 4; ++kt) {
        const float* xr = xr0 + kt * 32;
        float4 x0 = *reinterpret_cast<const float4*>(xr);
        float4 x1 = *reinterpret_cast<const float4*>(xr + 4);
        u32x4 bu;
        bu.x = pack_bf16(x0.x, x0.y);
        bu.y = pack_bf16(x0.z, x0.w);
        bu.z = pack_bf16(x1.x, x1.y);
        bu.w = pack_bf16(x1.z, x1.w);
        bf16x8 bfrag = __builtin_bit_cast(bf16x8, bu);
        #pragma unroll
        for (int ct = 0; ct < 8; ++ct) {
            bf16x8 afrag = *reinterpret_cast<const bf16x8*>(
                &wf[(((kt * 8 + ct) * 64) + lane) * 8]);
            acc[ct] = __builtin_amdgcn_mfma_f32_16x16x32_bf16(
                afrag, bfrag, acc[ct], 0, 0, 0);
        }
    }

    int row = rowbase + (lane & 15);
    int qd  = lane >> 4;             // col quad within ct-tile
    unsigned int* yrow = Y + (size_t)row * (D_N / 2);
    #pragma unroll
    for (int ct = 0; ct < 8; ++ct) {
        u32x2 yy;
        yy.x = pack_bf16(acc[ct][0], acc[ct][1]);
        yy.y = pack_bf16(acc[ct][2], acc[ct][3]);
        *reinterpret_cast<u32x2*>(yrow + ct * 8 + qd * 2) = yy;
    }
}

// ---------------------------------------------------------------------------
// Count + rank: one membership per thread; atomic return value = rank.
// ---------------------------------------------------------------------------
__global__ __launch_bounds__(256) void count_kernel(
    const int* __restrict__ eu, const int* __restrict__ ei,
    int* __restrict__ offs, int* __restrict__ rank_u, int* __restrict__ rank_i)
{
    int t = blockIdx.x * 256 + threadIdx.x;
    if (t >= NMEMB) return;
    if (t < NEDGE) {
        int e = t;
        int key = eu[e] * 4 + e / E_N;
        rank_u[e] = atomicAdd(&offs[key], 1);
    } else {
        int e = t - NEDGE;
        int key = NKEYU + ei[e] * 4 + e / E_N;
        rank_i[e] = atomicAdd(&offs[key], 1);
    }
}

// ---------------------------------------------------------------------------
// In-place hierarchical exclusive scan over offs[NKEYS].
// ---------------------------------------------------------------------------
__global__ __launch_bounds__(256) void scan1_kernel(
    int* __restrict__ offs, int* __restrict__ bsum)
{
    __shared__ int s[256];
    int base = blockIdx.x * SCHUNK + threadIdx.x * 8;
    int v[8]; int tsum = 0;
    #pragma unroll
    for (int j = 0; j < 8; ++j) {
        int idx = base + j;
        v[j] = (idx < NKEYS) ? offs[idx] : 0;
        tsum += v[j];
    }
    s[threadIdx.x] = tsum; __syncthreads();
    for (int off = 1; off < 256; off <<= 1) {
        int t = (threadIdx.x >= off) ? s[threadIdx.x - off] : 0;
        __syncthreads(); s[threadIdx.x] += t; __syncthreads();
    }
    int excl = s[threadIdx.x] - tsum;
    if (threadIdx.x == 255) bsum[blockIdx.x] = s[255];
    int run = excl;
    #pragma unroll
    for (int j = 0; j < 8; ++j) {
        int idx = base + j;
        if (idx < NKEYS) offs[idx] = run;
        run += v[j];
    }
}

__global__ __launch_bounds__(512) void scan2_kernel(int* __restrict__ bsum,
                                                    int* __restrict__ offs)
{
    __shared__ int s[512];
    int v = (threadIdx.x < SNBLK) ? bsum[threadIdx.x] : 0;
    s[threadIdx.x] = v; __syncthreads();
    for (int off = 1; off < 512; off <<= 1) {
        int t = (threadIdx.x >= off) ? s[threadIdx.x - off] : 0;
        __syncthreads(); s[threadIdx.x] += t; __syncthreads();
    }
    if (threadIdx.x < SNBLK) bsum[threadIdx.x] = s[threadIdx.x] - v;
    if (threadIdx.x == 511) offs[NKEYS] = s[511];
}

__global__ __launch_bounds__(256) void scan3_kernel(int* __restrict__ offs,
                                                    const int* __restrict__ bsum)
{
    int add = bsum[blockIdx.x];
    int base = blockIdx.x * SCHUNK + threadIdx.x * 8;
    #pragma unroll
    for (int j = 0; j < 8; ++j) {
        int idx = base + j;
        if (idx < NKEYS) offs[idx] += add;
    }
}

// ---------------------------------------------------------------------------
// Atomic-free fill: pos = offs[key] + precomputed rank. Pair packed to 4 B:
// src (low 17 bits) | rounded float-top-15 weight bits (high 15).
// ---------------------------------------------------------------------------
__global__ __launch_bounds__(256) void fill_kernel(
    const int* __restrict__ eu, const int* __restrict__ ei,
    const float* __restrict__ ew,
    const int* __restrict__ offs,
    const int* __restrict__ rank_u, const int* __restrict__ rank_i,
    unsigned int* __restrict__ pairs)
{
    int t = blockIdx.x * 256 + threadIdx.x;
    if (t >= NMEMB) return;
    if (t < NEDGE) {
        int e = t;
        int b = e / E_N;
        int key = eu[e] * 4 + b;
        int pos = offs[key] + rank_u[e];
        unsigned int wb = __float_as_uint(ew[e]) + 0x10000u;  // round bit 17
        pairs[pos] = (wb & W_MASK) | (unsigned int)ei[e];
    } else {
        int e = t - NEDGE;
        int b = e / E_N;
        int key = NKEYU + ei[e] * 4 + b;
        int pos = offs[key] + rank_i[e];
        unsigned int wb = __float_as_uint(ew[e]) + 0x10000u;
        pairs[pos] = (wb & W_MASK) | (unsigned int)eu[e];
    }
}

// ---------------------------------------------------------------------------
// Gather (one side per dispatch): one wave per destination row; lane owns
// 2 dims (1 uint of 2 bf16). 4 behavior buckets in lockstep, x2-unrolled:
// 8 memberships in flight. Pair loads wave-uniform -> scalar path.
// NT stores for outputs keep L2 for the bf16 row pool.
// ---------------------------------------------------------------------------
__global__ __launch_bounds__(256) void gather_kernel(
    const unsigned int* __restrict__ T,
    const unsigned int* __restrict__ pairs, const int* __restrict__ offs,
    float* __restrict__ single, float* __restrict__ multi,
    int N, int keybase, const float* __restrict__ alpha_p)
{
    int r = blockIdx.x * 4 + (threadIdx.x >> 6);
    if (r >= N) return;
    int k0 = keybase + r * 4;

    float alpha = alpha_p[0];
    int lane = threadIdx.x & 63;

    int o0 = __builtin_amdgcn_readfirstlane(offs[k0]);
    int o1 = __builtin_amdgcn_readfirstlane(offs[k0 + 1]);
    int o2 = __builtin_amdgcn_readfirstlane(offs[k0 + 2]);
    int o3 = __builtin_amdgcn_readfirstlane(offs[k0 + 3]);
    int o4 = __builtin_amdgcn_readfirstlane(offs[k0 + 4]);
    int p0 = o0, p1 = o1, p2 = o2, p3 = o3;

    float ax0 = 0.f, ay0 = 0.f, ax1 = 0.f, ay1 = 0.f;
    float ax2 = 0.f, ay2 = 0.f, ax3 = 0.f, ay3 = 0.f;

    while ((p0 < o1) | (p1 < o2) | (p2 < o3) | (p3 < o4)) {
        int a0 = p0 < o1, b0 = (p0 + 1) < o1;
        int a1 = p1 < o2, b1 = (p1 + 1) < o2;
        int a2 = p2 < o3, b2 = (p2 + 1) < o3;
        int a3 = p3 < o4, b3 = (p3 + 1) < o4;
        int i0a = a0 ? p0 : o0;         int i0b = b0 ? (p0 + 1) : i0a;
        int i1a = a1 ? p1 : o0;         int i1b = b1 ? (p1 + 1) : i1a;
        int i2a = a2 ? p2 : o0;         int i2b = b2 ? (p2 + 1) : i2a;
        int i3a = a3 ? p3 : o0;         int i3b = b3 ? (p3 + 1) : i3a;
        unsigned int s0a = __builtin_amdgcn_readfirstlane(pairs[i0a]);
        unsigned int s0b = __builtin_amdgcn_readfirstlane(pairs[i0b]);
        unsigned int s1a = __builtin_amdgcn_readfirstlane(pairs[i1a]);
        unsigned int s1b = __builtin_amdgcn_readfirstlane(pairs[i1b]);
        unsigned int s2a = __builtin_amdgcn_readfirstlane(pairs[i2a]);
        unsigned int s2b = __builtin_amdgcn_readfirstlane(pairs[i2b]);
        unsigned int s3a = __builtin_amdgcn_readfirstlane(pairs[i3a]);
        unsigned int s3b = __builtin_amdgcn_readfirstlane(pairs[i3b]);
        unsigned int d0a = T[(size_t)(s0a & SRC_MASK) * (D_N / 2) + lane];
        unsigned int d0b = T[(size_t)(s0b & SRC_MASK) * (D_N / 2) + lane];
        unsigned int d1a = T[(size_t)(s1a & SRC_MASK) * (D_N / 2) + lane];
        unsigned int d1b = T[(size_t)(s1b & SRC_MASK) * (D_N / 2) + lane];
        unsigned int d2a = T[(size_t)(s2a & SRC_MASK) * (D_N / 2) + lane];
        unsigned int d2b = T[(size_t)(s2b & SRC_MASK) * (D_N / 2) + lane];
        unsigned int d3a = T[(size_t)(s3a & SRC_MASK) * (D_N / 2) + lane];
        unsigned int d3b = T[(size_t)(s3b & SRC_MASK) * (D_N / 2) + lane];
        float w0a = a0 ? __uint_as_float(s0a & W_MASK) : 0.f;
        float w0b = b0 ? __uint_as_float(s0b & W_MASK) : 0.f;
        float w1a = a1 ? __uint_as_float(s1a & W_MASK) : 0.f;
        float w1b = b1 ? __uint_as_float(s1b & W_MASK) : 0.f;
        float w2a = a2 ? __uint_as_float(s2a & W_MASK) : 0.f;
        float w2b = b2 ? __uint_as_float(s2b & W_MASK) : 0.f;
        float w3a = a3 ? __uint_as_float(s3a & W_MASK) : 0.f;
        float w3b = b3 ? __uint_as_float(s3b & W_MASK) : 0.f;
        ax0 += w0a * __uint_as_float(d0a << 16)
             + w0b * __uint_as_float(d0b << 16);
        ay0 += w0a * __uint_as_float(d0a & 0xFFFF0000u)
             + w0b * __uint_as_float(d0b & 0xFFFF0000u);
        ax1 += w1a * __uint_as_float(d1a << 16)
             + w1b * __uint_as_float(d1b << 16);
        ay1 += w1a * __uint_as_float(d1a & 0xFFFF0000u)
             + w1b * __uint_as_float(d1b & 0xFFFF0000u);
        ax2 += w2a * __uint_as_float(d2a << 16)
             + w2b * __uint_as_float(d2b << 16);
        ay2 += w2a * __uint_as_float(d2a & 0xFFFF0000u)
             + w2b * __uint_as_float(d2b & 0xFFFF0000u);
        ax3 += w3a * __uint_as_float(d3a << 16)
             + w3b * __uint_as_float(d3b << 16);
        ay3 += w3a * __uint_as_float(d3a & 0xFFFF0000u)
             + w3b * __uint_as_float(d3b & 0xFFFF0000u);
        p0 += a0 + b0; p1 += a1 + b1; p2 += a2 + b2; p3 += a3 + b3;
    }

    float mx = 0.25f * (ax0 + ax1 + ax2 + ax3);
    float my = 0.25f * (ay0 + ay1 + ay2 + ay3);

    f32x2 o;
    o.x = ax0 >= 0.f ? ax0 : alpha * ax0;
    o.y = ay0 >= 0.f ? ay0 : alpha * ay0;
    __builtin_nontemporal_store(o, reinterpret_cast<f32x2*>(
        single + ((size_t)0 * N + r) * D_N + lane * 2));
    o.x = ax1 >= 0.f ? ax1 : alpha * ax1;
    o.y = ay1 >= 0.f ? ay1 : alpha * ay1;
    __builtin_nontemporal_store(o, reinterpret_cast<f32x2*>(
        single + ((size_t)1 * N + r) * D_N + lane * 2));
    o.x = ax2 >= 0.f ? ax2 : alpha * ax2;
    o.y = ay2 >= 0.f ? ay2 : alpha * ay2;
    __builtin_nontemporal_store(o, reinterpret_cast<f32x2*>(
        single + ((size_t)2 * N + r) * D_N + lane * 2));
    o.x = ax3 >= 0.f ? ax3 : alpha * ax3;
    o.y = ay3 >= 0.f ? ay3 : alpha * ay3;
    __builtin_nontemporal_store(o, reinterpret_cast<f32x2*>(
        single + ((size_t)3 * N + r) * D_N + lane * 2));

    o.x = mx >= 0.f ? mx : alpha * mx;
    o.y = my >= 0.f ? my : alpha * my;
    __builtin_nontemporal_store(o, reinterpret_cast<f32x2*>(
        multi + (size_t)r * D_N + lane * 2));
}

extern "C" void kernel_launch(void* const* d_in, const int* in_sizes, int n_in,
                              void* d_out, int out_size, void* d_ws, size_t ws_size,
                              hipStream_t stream) {
    const float* user_emb = (const float*)d_in[0];
    const float* item_emb = (const float*)d_in[1];
    const int*   eu       = (const int*)d_in[2];
    const int*   ei       = (const int*)d_in[3];
    const float* ew       = (const float*)d_in[4];
    const float* u_w      = (const float*)d_in[5];
    const float* i_w      = (const float*)d_in[6];
    const float* alpha    = (const float*)d_in[7];

    float* out      = (float*)d_out;
    float* multi_u  = out;                                      // [U][D]
    float* multi_i  = out + (size_t)U_N * D_N;                  // [I][D]
    float* single_u = out + (size_t)(U_N + I_N) * D_N;          // [B][U][D]
    float* single_i = single_u + (size_t)B_N * U_N * D_N;       // [B][I][D]

    // ranks live in multi_i's slot (consumed by fill; gather writes after).
    int* rank_u = (int*)multi_i;                                // 8 MB
    int* rank_i = rank_u + NEDGE;                               // 8 MB

    // d_ws: offs | bsum | pairs(4B packed) | tA(bf16) | tB(bf16) (~57 MB)
    int*  offs  = (int*)d_ws;                                   // NKEYS+4
    int*  bsum  = offs + (NKEYS + 4);                           // 512
    unsigned int* pairs =
        (unsigned int*)((char*)d_ws + ((((NKEYS + 4 + 512) * 4) + 255) & ~255));
    unsigned int* tA = pairs + NMEMB;                           // [I][64] 12.8 MB
    unsigned int* tB = tA + (size_t)I_N * (D_N / 2);            // [U][64] 25.6 MB

    transform_mfma_kernel<<<TB2I + TB2U + ZB, 256, 0, stream>>>(
        item_emb, user_emb, u_w, i_w, tA, tB, (int4*)offs);
    count_kernel<<<CB, 256, 0, stream>>>(eu, ei, offs, rank_u, rank_i);
    scan1_kernel<<<SNBLK, 256, 0, stream>>>(offs, bsum);
    scan2_kernel<<<1, 512, 0, stream>>>(bsum, offs);
    scan3_kernel<<<SNBLK, 256, 0, stream>>>(offs, bsum);
    fill_kernel<<<CB, 256, 0, stream>>>(eu, ei, ew, offs,
                                        rank_u, rank_i, pairs);
    // split by side: per-dispatch working set = one bf16 pool only
    gather_kernel<<<(U_N + 3) / 4, 256, 0, stream>>>(
        tA, pairs, offs, single_u, multi_u, U_N, 0, alpha);
    gather_kernel<<<(I_N + 3) / 4, 256, 0, stream>>>(
        tB, pairs, offs, single_i, multi_i, I_N, NKEYU, alpha);
}